// Round 1
// baseline (1305.326 us; speedup 1.0000x reference)
//
#include <hip/hip_runtime.h>
#include <cstddef>

// Problem constants (fixed by the reference setup)
constexpr int NN = 100000;          // nodes
constexpr int NE = 1600000;         // edges (without self loops)
constexpr int TE = NE + NN;         // edges + self loops = 1,700,000
constexpr int NG = 64;              // graphs
constexpr float EPS = 1e-5f;
constexpr float NEG_SLOPE = 0.2f;

// ---------------- CSR build ----------------

__global__ void k_deg(const int* __restrict__ ei, int* __restrict__ deg) {
    int e = blockIdx.x * blockDim.x + threadIdx.x;
    if (e >= TE) return;
    int d = (e < NE) ? ei[NE + e] : (e - NE);
    atomicAdd(&deg[d], 1);
}

#define SCAN_B 256
__global__ void k_scan1(const int* __restrict__ deg, int* __restrict__ partial, int n) {
    __shared__ int ls[SCAN_B];
    int i = blockIdx.x * SCAN_B + threadIdx.x;
    ls[threadIdx.x] = (i < n) ? deg[i] : 0;
    __syncthreads();
    for (int off = SCAN_B / 2; off; off >>= 1) {
        if (threadIdx.x < off) ls[threadIdx.x] += ls[threadIdx.x + off];
        __syncthreads();
    }
    if (threadIdx.x == 0) partial[blockIdx.x] = ls[0];
}

__global__ void k_scan2(int* __restrict__ partial, int nb, int* __restrict__ rowptr, int n) {
    if (threadIdx.x == 0 && blockIdx.x == 0) {
        int acc = 0;
        for (int i = 0; i < nb; ++i) { int v = partial[i]; partial[i] = acc; acc += v; }
        rowptr[n] = acc;   // == TE
    }
}

__global__ void k_scan3(const int* __restrict__ deg, const int* __restrict__ partial,
                        int* __restrict__ rowptr, int n) {
    __shared__ int ls[SCAN_B];
    int i = blockIdx.x * SCAN_B + threadIdx.x;
    int v = (i < n) ? deg[i] : 0;
    ls[threadIdx.x] = v;
    __syncthreads();
    for (int off = 1; off < SCAN_B; off <<= 1) {
        int add = (threadIdx.x >= off) ? ls[threadIdx.x - off] : 0;
        __syncthreads();
        ls[threadIdx.x] += add;
        __syncthreads();
    }
    if (i < n) rowptr[i] = partial[blockIdx.x] + ls[threadIdx.x] - v;  // exclusive
}

__global__ void k_fill(const int* __restrict__ ei, const int* __restrict__ rowptr,
                       int* __restrict__ cursor, int* __restrict__ colsrc) {
    int e = blockIdx.x * blockDim.x + threadIdx.x;
    if (e >= TE) return;
    int s, d;
    if (e < NE) { s = ei[e]; d = ei[NE + e]; } else { s = e - NE; d = e - NE; }
    int pos = atomicAdd(&cursor[d], 1);
    colsrc[rowptr[d] + pos] = s;
}

// ---------------- Node transform: h = x @ W ; al_s/al_d dots ----------------
// NB nodes per block, W staged in LDS. a_src/a_dst are [2, C] flat.

template <int IN, int OUT, int C, int NB>
__global__ void k_transform(const float* __restrict__ x, const float* __restrict__ W,
                            const float* __restrict__ a_src, const float* __restrict__ a_dst,
                            float* __restrict__ h, float* __restrict__ als,
                            float* __restrict__ ald, int n) {
    __shared__ float Ws[IN * OUT];
    __shared__ float xs[NB * IN];
    __shared__ float hs[NB * OUT];
    int node0 = blockIdx.x * NB;
    for (int i = threadIdx.x; i < IN * OUT; i += blockDim.x) Ws[i] = W[i];
    for (int i = threadIdx.x; i < NB * IN; i += blockDim.x) {
        int nn = node0 + i / IN;
        xs[i] = (nn < n) ? x[(size_t)nn * IN + (i % IN)] : 0.f;
    }
    __syncthreads();
    for (int o = threadIdx.x; o < NB * OUT; o += blockDim.x) {
        int nl = o / OUT, oc = o % OUT;
        float acc = 0.f;
#pragma unroll
        for (int i = 0; i < IN; ++i) acc += xs[nl * IN + i] * Ws[i * OUT + oc];
        hs[nl * OUT + oc] = acc;
        int nn = node0 + nl;
        if (nn < n) h[(size_t)nn * OUT + oc] = acc;
    }
    __syncthreads();
    for (int t = threadIdx.x; t < NB * 4; t += blockDim.x) {
        int nl = t >> 2, head = (t >> 1) & 1, sd = t & 1;
        const float* a = sd ? a_dst : a_src;
        float acc = 0.f;
        for (int c = 0; c < C; ++c) acc += hs[nl * OUT + head * C + c] * a[head * C + c];
        int nn = node0 + nl;
        if (nn < n) (sd ? ald : als)[nn * 2 + head] = acc;
    }
}

// ---------------- Aggregation: wave per dst node ----------------

__device__ __forceinline__ float lrelu(float v) { return v > 0.f ? v : NEG_SLOPE * v; }

template <int OUT>
__global__ void k_aggregate(const int* __restrict__ rowptr, const int* __restrict__ colsrc,
                            const float* __restrict__ h, const float* __restrict__ als,
                            const float* __restrict__ ald, float* __restrict__ out) {
    constexpr int C = OUT / 2;
    int wid = (int)((blockIdx.x * blockDim.x + threadIdx.x) >> 6);
    int lane = threadIdx.x & 63;
    if (wid >= NN) return;
    int start = rowptr[wid], end = rowptr[wid + 1];
    float d0v = ald[wid * 2 + 0], d1v = ald[wid * 2 + 1];

    // pass 1: per-head max of leaky_relu(score)
    float m0 = -1e30f, m1 = -1e30f;
    for (int e = start + lane; e < end; e += 64) {
        int s = colsrc[e];
        float t0 = lrelu(als[s * 2 + 0] + d0v);
        float t1 = lrelu(als[s * 2 + 1] + d1v);
        m0 = fmaxf(m0, t0); m1 = fmaxf(m1, t1);
    }
#pragma unroll
    for (int off = 32; off; off >>= 1) {
        m0 = fmaxf(m0, __shfl_xor(m0, off, 64));
        m1 = fmaxf(m1, __shfl_xor(m1, off, 64));
    }
    // pass 2: denominator
    float den0 = 0.f, den1 = 0.f;
    for (int e = start + lane; e < end; e += 64) {
        int s = colsrc[e];
        float t0 = lrelu(als[s * 2 + 0] + d0v);
        float t1 = lrelu(als[s * 2 + 1] + d1v);
        den0 += __expf(t0 - m0); den1 += __expf(t1 - m1);
    }
#pragma unroll
    for (int off = 32; off; off >>= 1) {
        den0 += __shfl_xor(den0, off, 64);
        den1 += __shfl_xor(den1, off, 64);
    }
    float inv0 = 1.f / den0, inv1 = 1.f / den1;

    // pass 3: serial over edges, lanes = channels
    if constexpr (OUT == 128) {
        float a0 = 0.f, a1 = 0.f;
        for (int e = start; e < end; ++e) {
            int s = colsrc[e];
            float t0 = lrelu(als[s * 2 + 0] + d0v);
            float t1 = lrelu(als[s * 2 + 1] + d1v);
            float w0 = __expf(t0 - m0) * inv0;
            float w1 = __expf(t1 - m1) * inv1;
            a0 += w0 * h[(size_t)s * OUT + lane];
            a1 += w1 * h[(size_t)s * OUT + 64 + lane];
        }
        out[(size_t)wid * OUT + lane] = a0;
        out[(size_t)wid * OUT + 64 + lane] = a1;
    } else {
        int c = lane;
        bool act = c < OUT;
        float a0 = 0.f;
        for (int e = start; e < end; ++e) {
            int s = colsrc[e];
            float t0 = lrelu(als[s * 2 + 0] + d0v);
            float t1 = lrelu(als[s * 2 + 1] + d1v);
            float w = (c < C) ? __expf(t0 - m0) * inv0 : __expf(t1 - m1) * inv1;
            if (act) a0 += w * h[(size_t)s * OUT + c];
        }
        if (act) out[(size_t)wid * OUT + c] = a0;
    }
}

// ---------------- BatchNorm (+ReLU). Bias b cancels under BN mean-subtract. ----------------

template <int OUT>
__global__ void k_bnstats(const float* __restrict__ h, float* __restrict__ sums, int n) {
    __shared__ float ls[256], lss[256];
    int c = threadIdx.x % OUT;
    int row0 = (int)((blockIdx.x * blockDim.x + threadIdx.x) / OUT);
    int stride = (int)(gridDim.x * blockDim.x / OUT);
    float s = 0.f, ss = 0.f;
    for (int r = row0; r < n; r += stride) {
        float v = h[(size_t)r * OUT + c];
        s += v; ss += v * v;
    }
    ls[threadIdx.x] = s; lss[threadIdx.x] = ss;
    __syncthreads();
    if (threadIdx.x < OUT) {
        float a = 0.f, b = 0.f;
        for (int t = threadIdx.x; t < 256; t += OUT) { a += ls[t]; b += lss[t]; }
        atomicAdd(&sums[c], a);
        atomicAdd(&sums[OUT + c], b);
    }
}

template <int OUT>
__global__ void k_bnfinal(const float* __restrict__ sums, const float* __restrict__ gamma,
                          const float* __restrict__ beta, float* __restrict__ sc, int n) {
    int c = threadIdx.x;
    if (c < OUT) {
        float mu = sums[c] / n;
        float var = sums[OUT + c] / n - mu * mu;
        float s = gamma[c] * rsqrtf(var + EPS);
        sc[c] = s;
        sc[OUT + c] = beta[c] - mu * s;
    }
}

template <int OUT>
__global__ void k_bnapply(float* __restrict__ h, const float* __restrict__ sc, int total) {
    int i = blockIdx.x * blockDim.x + threadIdx.x;
    int stride = gridDim.x * blockDim.x;
    for (; i < total; i += stride) {
        int c = i & (OUT - 1);
        float v = h[i] * sc[c] + sc[OUT + c];
        h[i] = v > 0.f ? v : 0.f;
    }
}

// ---------------- Pooling (segment max over sorted batch) + FC ----------------
// Post-ReLU values are >= 0, so int-bit atomicMax with 0-init is exact.

__global__ void k_pool(const float* __restrict__ h, const int* __restrict__ batch,
                       float* __restrict__ pooled, int n) {
    const int K = 128;
    int c = threadIdx.x;            // 0..127
    int n0 = blockIdx.x * K;
    if (n0 >= n) return;
    int nend = min(n, n0 + K);
    int curg = batch[n0];
    float m = 0.f;
    for (int nn = n0; nn < nend; ++nn) {
        int g = batch[nn];
        if (g != curg) {
            atomicMax((int*)&pooled[curg * 128 + c], __float_as_int(m));
            m = 0.f; curg = g;
        }
        m = fmaxf(m, h[(size_t)nn * 128 + c]);
    }
    atomicMax((int*)&pooled[curg * 128 + c], __float_as_int(m));
}

__global__ void k_fc(const float* __restrict__ pooled, const float* __restrict__ fcw,
                     const float* __restrict__ fcb, float* __restrict__ out) {
    int t = threadIdx.x;
    if (t >= NG * 10) return;
    int g = t / 10, j = t % 10;
    float acc = fcb[j];
#pragma unroll
    for (int c = 0; c < 128; ++c) acc += pooled[g * 128 + c] * fcw[c * 10 + j];
    out[g * 10 + j] = acc;
}

// ---------------- Host launch ----------------

extern "C" void kernel_launch(void* const* d_in, const int* in_sizes, int n_in,
                              void* d_out, int out_size, void* d_ws, size_t ws_size,
                              hipStream_t stream) {
    const float* x   = (const float*)d_in[0];
    const int*   ei  = (const int*)d_in[1];
    const int*   bat = (const int*)d_in[2];
    const float* W1  = (const float*)d_in[3];
    const float* as1 = (const float*)d_in[4];
    const float* ad1 = (const float*)d_in[5];
    // d_in[6] = b1 (cancels under BN)
    const float* g1  = (const float*)d_in[7];
    const float* be1 = (const float*)d_in[8];
    const float* W2  = (const float*)d_in[9];
    const float* as2 = (const float*)d_in[10];
    const float* ad2 = (const float*)d_in[11];
    const float* g2  = (const float*)d_in[13];
    const float* be2 = (const float*)d_in[14];
    const float* W3  = (const float*)d_in[15];
    const float* as3 = (const float*)d_in[16];
    const float* ad3 = (const float*)d_in[17];
    const float* g3  = (const float*)d_in[19];
    const float* be3 = (const float*)d_in[20];
    const float* fcw = (const float*)d_in[21];
    const float* fcb = (const float*)d_in[22];
    float* out = (float*)d_out;

    char* w = (char*)d_ws;
    size_t off = 0;
    auto take = [&](size_t bytes) {
        void* p = w + off;
        off += (bytes + 255) & ~(size_t)255;
        return p;
    };
    int*   deg     = (int*)take((size_t)NN * 4);
    int*   cursor  = (int*)take((size_t)NN * 4);
    int*   rowptr  = (int*)take((size_t)(NN + 1) * 4);
    int*   partial = (int*)take(512 * 4);
    int*   colsrc  = (int*)take((size_t)TE * 4);
    float* al_s    = (float*)take((size_t)NN * 2 * 4);
    float* al_d    = (float*)take((size_t)NN * 2 * 4);
    float* bnsums  = (float*)take(256 * 4);
    float* bnscale = (float*)take(256 * 4);
    float* pooled  = (float*)take((size_t)NG * 128 * 4);
    float* h0      = (float*)take((size_t)NN * 128 * 4);
    float* h1      = (float*)take((size_t)NN * 128 * 4);

    // ---- CSR build ----
    hipMemsetAsync(deg, 0, (size_t)NN * 4, stream);
    k_deg<<<(TE + 255) / 256, 256, 0, stream>>>(ei, deg);
    int nb = (NN + SCAN_B - 1) / SCAN_B;   // 391
    k_scan1<<<nb, SCAN_B, 0, stream>>>(deg, partial, NN);
    k_scan2<<<1, 1, 0, stream>>>(partial, nb, rowptr, NN);
    k_scan3<<<nb, SCAN_B, 0, stream>>>(deg, partial, rowptr, NN);
    hipMemsetAsync(cursor, 0, (size_t)NN * 4, stream);
    k_fill<<<(TE + 255) / 256, 256, 0, stream>>>(ei, rowptr, cursor, colsrc);

    // ---- layer 1: 3 -> 32 (H=2, C=16) ----
    k_transform<3, 32, 16, 8><<<NN / 8, 256, 0, stream>>>(x, W1, as1, ad1, h0, al_s, al_d, NN);
    k_aggregate<32><<<(NN + 3) / 4, 256, 0, stream>>>(rowptr, colsrc, h0, al_s, al_d, h1);
    hipMemsetAsync(bnsums, 0, 2 * 32 * 4, stream);
    k_bnstats<32><<<512, 256, 0, stream>>>(h1, bnsums, NN);
    k_bnfinal<32><<<1, 32, 0, stream>>>(bnsums, g1, be1, bnscale, NN);
    k_bnapply<32><<<2048, 256, 0, stream>>>(h1, bnscale, NN * 32);

    // ---- layer 2: 32 -> 64 (H=2, C=32) ----
    k_transform<32, 64, 32, 8><<<NN / 8, 256, 0, stream>>>(h1, W2, as2, ad2, h0, al_s, al_d, NN);
    k_aggregate<64><<<(NN + 3) / 4, 256, 0, stream>>>(rowptr, colsrc, h0, al_s, al_d, h1);
    hipMemsetAsync(bnsums, 0, 2 * 64 * 4, stream);
    k_bnstats<64><<<512, 256, 0, stream>>>(h1, bnsums, NN);
    k_bnfinal<64><<<1, 64, 0, stream>>>(bnsums, g2, be2, bnscale, NN);
    k_bnapply<64><<<2048, 256, 0, stream>>>(h1, bnscale, NN * 64);

    // ---- layer 3: 64 -> 128 (H=2, C=64) ----
    k_transform<64, 128, 64, 8><<<NN / 8, 256, 0, stream>>>(h1, W3, as3, ad3, h0, al_s, al_d, NN);
    k_aggregate<128><<<(NN + 3) / 4, 256, 0, stream>>>(rowptr, colsrc, h0, al_s, al_d, h1);
    hipMemsetAsync(bnsums, 0, 2 * 128 * 4, stream);
    k_bnstats<128><<<512, 256, 0, stream>>>(h1, bnsums, NN);
    k_bnfinal<128><<<1, 128, 0, stream>>>(bnsums, g3, be3, bnscale, NN);
    k_bnapply<128><<<2048, 256, 0, stream>>>(h1, bnscale, NN * 128);

    // ---- pool + fc ----
    hipMemsetAsync(pooled, 0, (size_t)NG * 128 * 4, stream);
    k_pool<<<(NN + 127) / 128, 128, 0, stream>>>(h1, bat, pooled, NN);
    k_fc<<<1, 640, 0, stream>>>(pooled, fcw, fcb, out);
}

// Round 2
// 674.869 us; speedup vs baseline: 1.9342x; 1.9342x over previous
//
#include <hip/hip_runtime.h>
#include <cstddef>

// Problem constants (fixed by the reference setup)
constexpr int NN = 100000;          // nodes
constexpr int NE = 1600000;         // edges (without self loops)
constexpr int TE = NE + NN;         // edges + self loops = 1,700,000
constexpr int NG = 64;              // graphs
constexpr float EPS = 1e-5f;
constexpr float NEG_SLOPE = 0.2f;

// ---------------- CSR build ----------------

__global__ void k_deg(const int* __restrict__ ei, int* __restrict__ deg) {
    int e = blockIdx.x * blockDim.x + threadIdx.x;
    if (e >= TE) return;
    int d = (e < NE) ? ei[NE + e] : (e - NE);
    atomicAdd(&deg[d], 1);
}

#define SCAN_B 256
__global__ void k_scan1(const int* __restrict__ deg, int* __restrict__ partial, int n) {
    __shared__ int ls[SCAN_B];
    int i = blockIdx.x * SCAN_B + threadIdx.x;
    ls[threadIdx.x] = (i < n) ? deg[i] : 0;
    __syncthreads();
    for (int off = SCAN_B / 2; off; off >>= 1) {
        if (threadIdx.x < off) ls[threadIdx.x] += ls[threadIdx.x + off];
        __syncthreads();
    }
    if (threadIdx.x == 0) partial[blockIdx.x] = ls[0];
}

__global__ void k_scan2(int* __restrict__ partial, int nb, int* __restrict__ rowptr, int n) {
    if (threadIdx.x == 0 && blockIdx.x == 0) {
        int acc = 0;
        for (int i = 0; i < nb; ++i) { int v = partial[i]; partial[i] = acc; acc += v; }
        rowptr[n] = acc;   // == TE
    }
}

__global__ void k_scan3(const int* __restrict__ deg, const int* __restrict__ partial,
                        int* __restrict__ rowptr, int n) {
    __shared__ int ls[SCAN_B];
    int i = blockIdx.x * SCAN_B + threadIdx.x;
    int v = (i < n) ? deg[i] : 0;
    ls[threadIdx.x] = v;
    __syncthreads();
    for (int off = 1; off < SCAN_B; off <<= 1) {
        int add = (threadIdx.x >= off) ? ls[threadIdx.x - off] : 0;
        __syncthreads();
        ls[threadIdx.x] += add;
        __syncthreads();
    }
    if (i < n) rowptr[i] = partial[blockIdx.x] + ls[threadIdx.x] - v;  // exclusive
}

__global__ void k_fill(const int* __restrict__ ei, const int* __restrict__ rowptr,
                       int* __restrict__ cursor, int* __restrict__ colsrc) {
    int e = blockIdx.x * blockDim.x + threadIdx.x;
    if (e >= TE) return;
    int s, d;
    if (e < NE) { s = ei[e]; d = ei[NE + e]; } else { s = e - NE; d = e - NE; }
    int pos = atomicAdd(&cursor[d], 1);
    colsrc[rowptr[d] + pos] = s;
}

// ---------------- Node transform: h = bnrelu(x) @ W ; attention dots ----------------
// BN(+ReLU) of the PREVIOUS layer is fused into the LDS load (bias b of the GAT
// layer cancels under BN mean-subtraction, so it is dropped entirely).

template <int IN, int OUT, bool BN>
__global__ void k_transform(const float* __restrict__ x, const float* __restrict__ W,
                            const float* __restrict__ a_src, const float* __restrict__ a_dst,
                            const float* __restrict__ bnsc,   // [IN scale][IN shift]
                            float* __restrict__ h, float* __restrict__ als,
                            float* __restrict__ ald, int n) {
    constexpr int C = OUT / 2;       // channels per head
    constexpr int TPN = OUT / 4;     // threads per node (float4 per thread)
    constexpr int NB = 256 / TPN;    // nodes per block
    __shared__ float4 Ws4[IN * TPN];
    __shared__ float xs[NB * IN];
    int node0 = blockIdx.x * NB;
    float* Wsf = (float*)Ws4;
    for (int i = threadIdx.x; i < IN * OUT; i += 256) Wsf[i] = W[i];
    for (int i = threadIdx.x; i < NB * IN; i += 256) {
        int nn = node0 + i / IN, ic = i % IN;
        float v = (nn < n) ? x[(size_t)nn * IN + ic] : 0.f;
        if constexpr (BN) {
            v = v * bnsc[ic] + bnsc[IN + ic];
            v = v > 0.f ? v : 0.f;
        }
        xs[i] = v;
    }
    __syncthreads();
    int nl = threadIdx.x / TPN, q = threadIdx.x % TPN;
    int node = node0 + nl;
    float4 acc = {0.f, 0.f, 0.f, 0.f};
#pragma unroll
    for (int i = 0; i < IN; ++i) {
        float xv = xs[nl * IN + i];
        float4 w = Ws4[i * TPN + q];
        acc.x += xv * w.x; acc.y += xv * w.y; acc.z += xv * w.z; acc.w += xv * w.w;
    }
    if (node < n) *(float4*)&h[(size_t)node * OUT + q * 4] = acc;
    // attention dots: reduce acc . a over the TPN/2 threads of each (node, head)
    int hd = (q >= TPN / 2);
    int cc = (q - hd * (TPN / 2)) * 4;
    float4 as4 = *(const float4*)&a_src[hd * C + cc];
    float4 ad4 = *(const float4*)&a_dst[hd * C + cc];
    float ps = acc.x * as4.x + acc.y * as4.y + acc.z * as4.z + acc.w * as4.w;
    float pd = acc.x * ad4.x + acc.y * ad4.y + acc.z * ad4.z + acc.w * ad4.w;
#pragma unroll
    for (int m = 1; m < TPN / 2; m <<= 1) {
        ps += __shfl_xor(ps, m, 64);
        pd += __shfl_xor(pd, m, 64);
    }
    if ((q & (TPN / 2 - 1)) == 0 && node < n) {
        als[node * 2 + hd] = ps;
        ald[node * 2 + hd] = pd;
    }
}

// ---------------- Aggregation: wave per dst node ----------------

__device__ __forceinline__ float lrelu(float v) { return v > 0.f ? v : NEG_SLOPE * v; }

template <int OUT>
__global__ void k_aggregate(const int* __restrict__ rowptr, const int* __restrict__ colsrc,
                            const float* __restrict__ h, const float* __restrict__ als,
                            const float* __restrict__ ald, float* __restrict__ out) {
    constexpr int C = OUT / 2;
    constexpr int LPE = OUT / 4;   // lanes per edge (float4 channel groups)
    constexpr int EPI = 64 / LPE;  // edges per gather iteration
    int wid = (int)(((size_t)blockIdx.x * blockDim.x + threadIdx.x) >> 6);
    int lane = threadIdx.x & 63;
    if (wid >= NN) return;
    int start = rowptr[wid], end = rowptr[wid + 1];
    int cnt = end - start;
    float2 dv = ((const float2*)ald)[wid];

    if (cnt <= 64) {
        // ---- fast path: whole neighbor list fits one wave ----
        int e = start + lane;
        bool act = e < end;
        int s = act ? colsrc[e] : 0;                 // coalesced
        float2 av = act ? ((const float2*)als)[s] : make_float2(0.f, 0.f);
        float t0 = act ? lrelu(av.x + dv.x) : -1e30f;
        float t1 = act ? lrelu(av.y + dv.y) : -1e30f;
        float m0 = t0, m1 = t1;
#pragma unroll
        for (int off = 32; off; off >>= 1) {
            m0 = fmaxf(m0, __shfl_xor(m0, off, 64));
            m1 = fmaxf(m1, __shfl_xor(m1, off, 64));
        }
        float w0 = act ? __expf(t0 - m0) : 0.f;
        float w1 = act ? __expf(t1 - m1) : 0.f;
        int sub = lane / LPE, cl = lane % LPE;
        bool head1 = (cl >= LPE / 2);
        float4 acc = {0.f, 0.f, 0.f, 0.f};
        for (int j0 = 0; j0 < cnt; j0 += EPI) {
            int jj = j0 + sub;                        // < 64 always
            int sj = __shfl(s, jj, 64);
            float w0j = __shfl(w0, jj, 64);
            float w1j = __shfl(w1, jj, 64);
            float wsel = head1 ? w1j : w0j;           // 0 for jj >= cnt
            float4 hv = *(const float4*)&h[(size_t)sj * OUT + cl * 4];
            acc.x += wsel * hv.x; acc.y += wsel * hv.y;
            acc.z += wsel * hv.z; acc.w += wsel * hv.w;
        }
        // combine edge-slot partials
#pragma unroll
        for (int m = LPE; m < 64; m <<= 1) {
            acc.x += __shfl_xor(acc.x, m, 64);
            acc.y += __shfl_xor(acc.y, m, 64);
            acc.z += __shfl_xor(acc.z, m, 64);
            acc.w += __shfl_xor(acc.w, m, 64);
        }
        float den0 = w0, den1 = w1;
#pragma unroll
        for (int off = 32; off; off >>= 1) {
            den0 += __shfl_xor(den0, off, 64);
            den1 += __shfl_xor(den1, off, 64);
        }
        float inv = 1.f / (head1 ? den1 : den0);
        if (sub == 0) {
            float4 o = {acc.x * inv, acc.y * inv, acc.z * inv, acc.w * inv};
            *(float4*)&out[(size_t)wid * OUT + cl * 4] = o;
        }
    } else {
        // ---- slow generic path (deg > 64; essentially never taken) ----
        float m0 = -1e30f, m1 = -1e30f;
        for (int e = start + lane; e < end; e += 64) {
            int s = colsrc[e];
            float t0 = lrelu(als[s * 2 + 0] + dv.x);
            float t1 = lrelu(als[s * 2 + 1] + dv.y);
            m0 = fmaxf(m0, t0); m1 = fmaxf(m1, t1);
        }
#pragma unroll
        for (int off = 32; off; off >>= 1) {
            m0 = fmaxf(m0, __shfl_xor(m0, off, 64));
            m1 = fmaxf(m1, __shfl_xor(m1, off, 64));
        }
        float den0 = 0.f, den1 = 0.f;
        for (int e = start + lane; e < end; e += 64) {
            int s = colsrc[e];
            float t0 = lrelu(als[s * 2 + 0] + dv.x);
            float t1 = lrelu(als[s * 2 + 1] + dv.y);
            den0 += __expf(t0 - m0); den1 += __expf(t1 - m1);
        }
#pragma unroll
        for (int off = 32; off; off >>= 1) {
            den0 += __shfl_xor(den0, off, 64);
            den1 += __shfl_xor(den1, off, 64);
        }
        float inv0 = 1.f / den0, inv1 = 1.f / den1;
        if constexpr (OUT == 128) {
            float a0 = 0.f, a1 = 0.f;
            for (int e = start; e < end; ++e) {
                int s = colsrc[e];
                float t0 = lrelu(als[s * 2 + 0] + dv.x);
                float t1 = lrelu(als[s * 2 + 1] + dv.y);
                float w0 = __expf(t0 - m0) * inv0;
                float w1 = __expf(t1 - m1) * inv1;
                a0 += w0 * h[(size_t)s * OUT + lane];
                a1 += w1 * h[(size_t)s * OUT + 64 + lane];
            }
            out[(size_t)wid * OUT + lane] = a0;
            out[(size_t)wid * OUT + 64 + lane] = a1;
        } else {
            int c = lane;
            bool act2 = c < OUT;
            float a0 = 0.f;
            for (int e = start; e < end; ++e) {
                int s = colsrc[e];
                float t0 = lrelu(als[s * 2 + 0] + dv.x);
                float t1 = lrelu(als[s * 2 + 1] + dv.y);
                float w = (c < C) ? __expf(t0 - m0) * inv0 : __expf(t1 - m1) * inv1;
                if (act2) a0 += w * h[(size_t)s * OUT + c];
            }
            if (act2) out[(size_t)wid * OUT + c] = a0;
        }
    }
}

// ---------------- BatchNorm stats (apply is fused into consumers) ----------------

template <int OUT>
__global__ void k_bnstats(const float* __restrict__ h, float* __restrict__ sums, int n) {
    __shared__ float ls[256], lss[256];
    int c = threadIdx.x % OUT;
    int row0 = (int)((blockIdx.x * blockDim.x + threadIdx.x) / OUT);
    int stride = (int)(gridDim.x * blockDim.x / OUT);
    float s = 0.f, ss = 0.f;
    for (int r = row0; r < n; r += stride) {
        float v = h[(size_t)r * OUT + c];
        s += v; ss += v * v;
    }
    ls[threadIdx.x] = s; lss[threadIdx.x] = ss;
    __syncthreads();
    if (threadIdx.x < OUT) {
        float a = 0.f, b = 0.f;
        for (int t = threadIdx.x; t < 256; t += OUT) { a += ls[t]; b += lss[t]; }
        atomicAdd(&sums[c], a);
        atomicAdd(&sums[OUT + c], b);
    }
}

template <int OUT>
__global__ void k_bnfinal(const float* __restrict__ sums, const float* __restrict__ gamma,
                          const float* __restrict__ beta, float* __restrict__ sc, int n) {
    int c = threadIdx.x;
    if (c < OUT) {
        float mu = sums[c] / n;
        float var = sums[OUT + c] / n - mu * mu;
        float s = gamma[c] * rsqrtf(var + EPS);
        sc[c] = s;
        sc[OUT + c] = beta[c] - mu * s;
    }
}

// ---------------- Pooling (applies BN3+ReLU inline) + FC ----------------
// Post-ReLU values are >= 0, so int-bit atomicMax with 0-init is exact.

__global__ void k_pool(const float* __restrict__ h, const int* __restrict__ batch,
                       const float* __restrict__ sc, float* __restrict__ pooled, int n) {
    const int K = 128;
    int c = threadIdx.x;            // 0..127
    float scale = sc[c], shift = sc[128 + c];
    int n0 = blockIdx.x * K;
    if (n0 >= n) return;
    int nend = min(n, n0 + K);
    int curg = batch[n0];
    float m = 0.f;
    for (int nn = n0; nn < nend; ++nn) {
        int g = batch[nn];
        if (g != curg) {
            atomicMax((int*)&pooled[curg * 128 + c], __float_as_int(m));
            m = 0.f; curg = g;
        }
        float v = h[(size_t)nn * 128 + c] * scale + shift;
        m = fmaxf(m, v > 0.f ? v : 0.f);
    }
    atomicMax((int*)&pooled[curg * 128 + c], __float_as_int(m));
}

__global__ void k_fc(const float* __restrict__ pooled, const float* __restrict__ fcw,
                     const float* __restrict__ fcb, float* __restrict__ out) {
    int t = threadIdx.x;
    if (t >= NG * 10) return;
    int g = t / 10, j = t % 10;
    float acc = fcb[j];
#pragma unroll
    for (int c = 0; c < 128; ++c) acc += pooled[g * 128 + c] * fcw[c * 10 + j];
    out[g * 10 + j] = acc;
}

// ---------------- Host launch ----------------

extern "C" void kernel_launch(void* const* d_in, const int* in_sizes, int n_in,
                              void* d_out, int out_size, void* d_ws, size_t ws_size,
                              hipStream_t stream) {
    const float* x   = (const float*)d_in[0];
    const int*   ei  = (const int*)d_in[1];
    const int*   bat = (const int*)d_in[2];
    const float* W1  = (const float*)d_in[3];
    const float* as1 = (const float*)d_in[4];
    const float* ad1 = (const float*)d_in[5];
    // d_in[6] = b1 (cancels under BN)
    const float* g1  = (const float*)d_in[7];
    const float* be1 = (const float*)d_in[8];
    const float* W2  = (const float*)d_in[9];
    const float* as2 = (const float*)d_in[10];
    const float* ad2 = (const float*)d_in[11];
    const float* g2  = (const float*)d_in[13];
    const float* be2 = (const float*)d_in[14];
    const float* W3  = (const float*)d_in[15];
    const float* as3 = (const float*)d_in[16];
    const float* ad3 = (const float*)d_in[17];
    const float* g3  = (const float*)d_in[19];
    const float* be3 = (const float*)d_in[20];
    const float* fcw = (const float*)d_in[21];
    const float* fcb = (const float*)d_in[22];
    float* out = (float*)d_out;

    char* w = (char*)d_ws;
    size_t off = 0;
    auto take = [&](size_t bytes) {
        void* p = w + off;
        off += (bytes + 255) & ~(size_t)255;
        return p;
    };
    int*   deg     = (int*)take((size_t)NN * 4);
    int*   cursor  = (int*)take((size_t)NN * 4);
    int*   rowptr  = (int*)take((size_t)(NN + 1) * 4);
    int*   partial = (int*)take(512 * 4);
    int*   colsrc  = (int*)take((size_t)TE * 4);
    float* al_s    = (float*)take((size_t)NN * 2 * 4);
    float* al_d    = (float*)take((size_t)NN * 2 * 4);
    float* bnsums  = (float*)take(256 * 4);
    float* bnsc1   = (float*)take(64 * 4);
    float* bnsc2   = (float*)take(128 * 4);
    float* bnsc3   = (float*)take(256 * 4);
    float* pooled  = (float*)take((size_t)NG * 128 * 4);
    float* h0      = (float*)take((size_t)NN * 128 * 4);
    float* h1      = (float*)take((size_t)NN * 128 * 4);

    // ---- CSR build ----
    hipMemsetAsync(deg, 0, (size_t)NN * 4, stream);
    k_deg<<<(TE + 255) / 256, 256, 0, stream>>>(ei, deg);
    int nb = (NN + SCAN_B - 1) / SCAN_B;   // 391
    k_scan1<<<nb, SCAN_B, 0, stream>>>(deg, partial, NN);
    k_scan2<<<1, 1, 0, stream>>>(partial, nb, rowptr, NN);
    k_scan3<<<nb, SCAN_B, 0, stream>>>(deg, partial, rowptr, NN);
    hipMemsetAsync(cursor, 0, (size_t)NN * 4, stream);
    k_fill<<<(TE + 255) / 256, 256, 0, stream>>>(ei, rowptr, cursor, colsrc);

    const int AGG_BLOCKS = (NN + 3) / 4;   // 4 waves / block

    // ---- layer 1: 3 -> 32 (H=2, C=16) ----
    k_transform<3, 32, false><<<(NN + 31) / 32, 256, 0, stream>>>(
        x, W1, as1, ad1, nullptr, h0, al_s, al_d, NN);
    k_aggregate<32><<<AGG_BLOCKS, 256, 0, stream>>>(rowptr, colsrc, h0, al_s, al_d, h1);
    hipMemsetAsync(bnsums, 0, 2 * 32 * 4, stream);
    k_bnstats<32><<<512, 256, 0, stream>>>(h1, bnsums, NN);
    k_bnfinal<32><<<1, 32, 0, stream>>>(bnsums, g1, be1, bnsc1, NN);

    // ---- layer 2: 32 -> 64 (H=2, C=32) ----
    k_transform<32, 64, true><<<(NN + 15) / 16, 256, 0, stream>>>(
        h1, W2, as2, ad2, bnsc1, h0, al_s, al_d, NN);
    k_aggregate<64><<<AGG_BLOCKS, 256, 0, stream>>>(rowptr, colsrc, h0, al_s, al_d, h1);
    hipMemsetAsync(bnsums, 0, 2 * 64 * 4, stream);
    k_bnstats<64><<<512, 256, 0, stream>>>(h1, bnsums, NN);
    k_bnfinal<64><<<1, 64, 0, stream>>>(bnsums, g2, be2, bnsc2, NN);

    // ---- layer 3: 64 -> 128 (H=2, C=64) ----
    k_transform<64, 128, true><<<(NN + 7) / 8, 256, 0, stream>>>(
        h1, W3, as3, ad3, bnsc2, h0, al_s, al_d, NN);
    k_aggregate<128><<<AGG_BLOCKS, 256, 0, stream>>>(rowptr, colsrc, h0, al_s, al_d, h1);
    hipMemsetAsync(bnsums, 0, 2 * 128 * 4, stream);
    k_bnstats<128><<<512, 256, 0, stream>>>(h1, bnsums, NN);
    k_bnfinal<128><<<1, 128, 0, stream>>>(bnsums, g3, be3, bnsc3, NN);

    // ---- pool (BN3 fused) + fc ----
    hipMemsetAsync(pooled, 0, (size_t)NG * 128 * 4, stream);
    k_pool<<<(NN + 127) / 128, 128, 0, stream>>>(h1, bat, bnsc3, pooled, NN);
    k_fc<<<1, 640, 0, stream>>>(pooled, fcw, fcb, out);
}

// Round 3
// 611.946 us; speedup vs baseline: 2.1331x; 1.1028x over previous
//
#include <hip/hip_runtime.h>
#include <cstddef>

// Problem constants (fixed by the reference setup)
constexpr int NN = 100000;          // nodes
constexpr int NE = 1600000;         // edges (without self loops)
constexpr int TE = NE + NN;         // edges + self loops = 1,700,000
constexpr int NG = 64;              // graphs
constexpr float EPS = 1e-5f;
constexpr float NEG_SLOPE = 0.2f;

// bf16 helpers (RNE pack, exact unpack)
__device__ __forceinline__ unsigned short f2bf(float f) {
    unsigned u = __float_as_uint(f);
    u += 0x7fffu + ((u >> 16) & 1u);
    return (unsigned short)(u >> 16);
}
__device__ __forceinline__ float bf2f(unsigned short s) {
    return __uint_as_float((unsigned)s << 16);
}
__device__ __forceinline__ float bflo(unsigned u) { return __uint_as_float(u << 16); }
__device__ __forceinline__ float bfhi(unsigned u) { return __uint_as_float(u & 0xffff0000u); }

// ---------------- CSR build ----------------

__global__ void k_deg(const int* __restrict__ ei, int* __restrict__ deg) {
    int e = blockIdx.x * blockDim.x + threadIdx.x;
    if (e >= TE) return;
    int d = (e < NE) ? ei[NE + e] : (e - NE);
    atomicAdd(&deg[d], 1);
}

#define SCAN_B 256
__global__ void k_scan1(const int* __restrict__ deg, int* __restrict__ partial, int n) {
    __shared__ int ls[SCAN_B];
    int i = blockIdx.x * SCAN_B + threadIdx.x;
    ls[threadIdx.x] = (i < n) ? deg[i] : 0;
    __syncthreads();
    for (int off = SCAN_B / 2; off; off >>= 1) {
        if (threadIdx.x < off) ls[threadIdx.x] += ls[threadIdx.x + off];
        __syncthreads();
    }
    if (threadIdx.x == 0) partial[blockIdx.x] = ls[0];
}

// parallel exclusive scan of the (<=512) per-block partials
__global__ void k_scan2(int* __restrict__ partial, int nb, int* __restrict__ rowptr, int n) {
    __shared__ int ls[512];
    int t = threadIdx.x;
    int v = (t < nb) ? partial[t] : 0;
    ls[t] = v;
    __syncthreads();
    for (int off = 1; off < 512; off <<= 1) {
        int add = (t >= off) ? ls[t - off] : 0;
        __syncthreads();
        ls[t] += add;
        __syncthreads();
    }
    if (t < nb) partial[t] = ls[t] - v;   // exclusive
    if (t == 511) rowptr[n] = ls[511];    // total == TE
}

__global__ void k_scan3(const int* __restrict__ deg, const int* __restrict__ partial,
                        int* __restrict__ rowptr, int n) {
    __shared__ int ls[SCAN_B];
    int i = blockIdx.x * SCAN_B + threadIdx.x;
    int v = (i < n) ? deg[i] : 0;
    ls[threadIdx.x] = v;
    __syncthreads();
    for (int off = 1; off < SCAN_B; off <<= 1) {
        int add = (threadIdx.x >= off) ? ls[threadIdx.x - off] : 0;
        __syncthreads();
        ls[threadIdx.x] += add;
        __syncthreads();
    }
    if (i < n) rowptr[i] = partial[blockIdx.x] + ls[threadIdx.x] - v;  // exclusive
}

__global__ void k_fill(const int* __restrict__ ei, const int* __restrict__ rowptr,
                       int* __restrict__ cursor, int* __restrict__ colsrc) {
    int e = blockIdx.x * blockDim.x + threadIdx.x;
    if (e >= TE) return;
    int s, d;
    if (e < NE) { s = ei[e]; d = ei[NE + e]; } else { s = e - NE; d = e - NE; }
    int pos = atomicAdd(&cursor[d], 1);
    colsrc[rowptr[d] + pos] = s;
}

// ---------------- Node transform: h = bnrelu(x) @ W ; attention dots ----------------
// BN(+ReLU) of the PREVIOUS layer is fused into the LDS load (bias b of the GAT
// layer cancels under BN mean-subtraction, so it is dropped entirely).
// h is written as bf16 (the aggregate gather is its only consumer);
// attention logits als/ald stay fp32 (computed from fp32 accumulators).

template <int IN, int OUT, bool BN>
__global__ void k_transform(const float* __restrict__ x, const float* __restrict__ W,
                            const float* __restrict__ a_src, const float* __restrict__ a_dst,
                            const float* __restrict__ bnsc,   // [IN scale][IN shift]
                            unsigned short* __restrict__ h, float* __restrict__ als,
                            float* __restrict__ ald, int n) {
    constexpr int C = OUT / 2;       // channels per head
    constexpr int TPN = OUT / 4;     // threads per node (float4 per thread)
    constexpr int NB = 256 / TPN;    // nodes per block
    __shared__ float4 Ws4[IN * TPN];
    __shared__ float xs[NB * IN];
    int node0 = blockIdx.x * NB;
    float* Wsf = (float*)Ws4;
    for (int i = threadIdx.x; i < IN * OUT; i += 256) Wsf[i] = W[i];
    for (int i = threadIdx.x; i < NB * IN; i += 256) {
        int nn = node0 + i / IN, ic = i % IN;
        float v = (nn < n) ? x[(size_t)nn * IN + ic] : 0.f;
        if constexpr (BN) {
            v = v * bnsc[ic] + bnsc[IN + ic];
            v = v > 0.f ? v : 0.f;
        }
        xs[i] = v;
    }
    __syncthreads();
    int nl = threadIdx.x / TPN, q = threadIdx.x % TPN;
    int node = node0 + nl;
    float4 acc = {0.f, 0.f, 0.f, 0.f};
#pragma unroll
    for (int i = 0; i < IN; ++i) {
        float xv = xs[nl * IN + i];
        float4 w = Ws4[i * TPN + q];
        acc.x += xv * w.x; acc.y += xv * w.y; acc.z += xv * w.z; acc.w += xv * w.w;
    }
    if (node < n) {
        uint2 pk;
        pk.x = (unsigned)f2bf(acc.x) | ((unsigned)f2bf(acc.y) << 16);
        pk.y = (unsigned)f2bf(acc.z) | ((unsigned)f2bf(acc.w) << 16);
        *(uint2*)&h[(size_t)node * OUT + q * 4] = pk;
    }
    // attention dots: reduce acc . a over the TPN/2 threads of each (node, head)
    int hd = (q >= TPN / 2);
    int cc = (q - hd * (TPN / 2)) * 4;
    float4 as4 = *(const float4*)&a_src[hd * C + cc];
    float4 ad4 = *(const float4*)&a_dst[hd * C + cc];
    float ps = acc.x * as4.x + acc.y * as4.y + acc.z * as4.z + acc.w * as4.w;
    float pd = acc.x * ad4.x + acc.y * ad4.y + acc.z * ad4.z + acc.w * ad4.w;
#pragma unroll
    for (int m = 1; m < TPN / 2; m <<= 1) {
        ps += __shfl_xor(ps, m, 64);
        pd += __shfl_xor(pd, m, 64);
    }
    if ((q & (TPN / 2 - 1)) == 0 && node < n) {
        als[node * 2 + hd] = ps;
        ald[node * 2 + hd] = pd;
    }
}

// ---------------- Aggregation: wave per dst node, bf16 h gather ----------------

__device__ __forceinline__ float lrelu(float v) { return v > 0.f ? v : NEG_SLOPE * v; }

template <int OUT>
__global__ void k_aggregate(const int* __restrict__ rowptr, const int* __restrict__ colsrc,
                            const unsigned short* __restrict__ h, const float* __restrict__ als,
                            const float* __restrict__ ald, float* __restrict__ out) {
    constexpr int LPE = OUT / 8;   // lanes per edge (8 bf16 = 16B per lane)
    constexpr int EPI = 64 / LPE;  // edges per gather iteration
    int wid = (int)(((size_t)blockIdx.x * blockDim.x + threadIdx.x) >> 6);
    int lane = threadIdx.x & 63;
    if (wid >= NN) return;
    int start = rowptr[wid], end = rowptr[wid + 1];
    int cnt = end - start;
    float2 dv = ((const float2*)ald)[wid];

    if (cnt <= 64) {
        // ---- fast path: whole neighbor list fits one wave ----
        int e = start + lane;
        bool act = e < end;
        int s = act ? colsrc[e] : 0;                 // coalesced
        float2 av = act ? ((const float2*)als)[s] : make_float2(0.f, 0.f);
        float t0 = act ? lrelu(av.x + dv.x) : -1e30f;
        float t1 = act ? lrelu(av.y + dv.y) : -1e30f;
        float m0 = t0, m1 = t1;
#pragma unroll
        for (int off = 32; off; off >>= 1) {
            m0 = fmaxf(m0, __shfl_xor(m0, off, 64));
            m1 = fmaxf(m1, __shfl_xor(m1, off, 64));
        }
        float w0 = act ? __expf(t0 - m0) : 0.f;
        float w1 = act ? __expf(t1 - m1) : 0.f;
        int sub = lane / LPE, cl = lane % LPE;       // cl*8 = first channel
        bool head1 = (cl >= LPE / 2);
        float acc[8];
#pragma unroll
        for (int k = 0; k < 8; ++k) acc[k] = 0.f;
        for (int j0 = 0; j0 < cnt; j0 += EPI) {
            int jj = j0 + sub;                        // < 64 always
            int sj = __shfl(s, jj, 64);
            float w0j = __shfl(w0, jj, 64);
            float w1j = __shfl(w1, jj, 64);
            float wsel = head1 ? w1j : w0j;           // 0 for jj >= cnt
            uint4 hv = *(const uint4*)&h[(size_t)sj * OUT + cl * 8];
            acc[0] += wsel * bflo(hv.x); acc[1] += wsel * bfhi(hv.x);
            acc[2] += wsel * bflo(hv.y); acc[3] += wsel * bfhi(hv.y);
            acc[4] += wsel * bflo(hv.z); acc[5] += wsel * bfhi(hv.z);
            acc[6] += wsel * bflo(hv.w); acc[7] += wsel * bfhi(hv.w);
        }
        // combine edge-slot partials
#pragma unroll
        for (int m = LPE; m < 64; m <<= 1) {
#pragma unroll
            for (int k = 0; k < 8; ++k) acc[k] += __shfl_xor(acc[k], m, 64);
        }
        float den0 = w0, den1 = w1;
#pragma unroll
        for (int off = 32; off; off >>= 1) {
            den0 += __shfl_xor(den0, off, 64);
            den1 += __shfl_xor(den1, off, 64);
        }
        float inv = 1.f / (head1 ? den1 : den0);
        if (sub == 0) {
            float4 o0 = {acc[0] * inv, acc[1] * inv, acc[2] * inv, acc[3] * inv};
            float4 o1 = {acc[4] * inv, acc[5] * inv, acc[6] * inv, acc[7] * inv};
            *(float4*)&out[(size_t)wid * OUT + cl * 8] = o0;
            *(float4*)&out[(size_t)wid * OUT + cl * 8 + 4] = o1;
        }
    } else {
        // ---- slow generic path (deg > 64; essentially never taken) ----
        constexpr int C = OUT / 2;
        float m0 = -1e30f, m1 = -1e30f;
        for (int e = start + lane; e < end; e += 64) {
            int s = colsrc[e];
            float t0 = lrelu(als[s * 2 + 0] + dv.x);
            float t1 = lrelu(als[s * 2 + 1] + dv.y);
            m0 = fmaxf(m0, t0); m1 = fmaxf(m1, t1);
        }
#pragma unroll
        for (int off = 32; off; off >>= 1) {
            m0 = fmaxf(m0, __shfl_xor(m0, off, 64));
            m1 = fmaxf(m1, __shfl_xor(m1, off, 64));
        }
        float den0 = 0.f, den1 = 0.f;
        for (int e = start + lane; e < end; e += 64) {
            int s = colsrc[e];
            float t0 = lrelu(als[s * 2 + 0] + dv.x);
            float t1 = lrelu(als[s * 2 + 1] + dv.y);
            den0 += __expf(t0 - m0); den1 += __expf(t1 - m1);
        }
#pragma unroll
        for (int off = 32; off; off >>= 1) {
            den0 += __shfl_xor(den0, off, 64);
            den1 += __shfl_xor(den1, off, 64);
        }
        float inv0 = 1.f / den0, inv1 = 1.f / den1;
        if constexpr (OUT == 128) {
            float a0 = 0.f, a1 = 0.f;
            for (int e = start; e < end; ++e) {
                int s = colsrc[e];
                float t0 = lrelu(als[s * 2 + 0] + dv.x);
                float t1 = lrelu(als[s * 2 + 1] + dv.y);
                float w0 = __expf(t0 - m0) * inv0;
                float w1 = __expf(t1 - m1) * inv1;
                a0 += w0 * bf2f(h[(size_t)s * OUT + lane]);
                a1 += w1 * bf2f(h[(size_t)s * OUT + 64 + lane]);
            }
            out[(size_t)wid * OUT + lane] = a0;
            out[(size_t)wid * OUT + 64 + lane] = a1;
        } else {
            int c = lane;
            bool act2 = c < OUT;
            float a0 = 0.f;
            for (int e = start; e < end; ++e) {
                int s = colsrc[e];
                float t0 = lrelu(als[s * 2 + 0] + dv.x);
                float t1 = lrelu(als[s * 2 + 1] + dv.y);
                float w = (c < C) ? __expf(t0 - m0) * inv0 : __expf(t1 - m1) * inv1;
                if (act2) a0 += w * bf2f(h[(size_t)s * OUT + c]);
            }
            if (act2) out[(size_t)wid * OUT + c] = a0;
        }
    }
}

// ---------------- BatchNorm stats (apply is fused into consumers) ----------------

template <int OUT>
__global__ void k_bnstats(const float* __restrict__ h, float* __restrict__ sums, int n) {
    __shared__ float ls[256], lss[256];
    int c = threadIdx.x % OUT;
    int row0 = (int)((blockIdx.x * blockDim.x + threadIdx.x) / OUT);
    int stride = (int)(gridDim.x * blockDim.x / OUT);
    float s = 0.f, ss = 0.f;
    for (int r = row0; r < n; r += stride) {
        float v = h[(size_t)r * OUT + c];
        s += v; ss += v * v;
    }
    ls[threadIdx.x] = s; lss[threadIdx.x] = ss;
    __syncthreads();
    if (threadIdx.x < OUT) {
        float a = 0.f, b = 0.f;
        for (int t = threadIdx.x; t < 256; t += OUT) { a += ls[t]; b += lss[t]; }
        atomicAdd(&sums[c], a);
        atomicAdd(&sums[OUT + c], b);
    }
}

template <int OUT>
__global__ void k_bnfinal(const float* __restrict__ sums, const float* __restrict__ gamma,
                          const float* __restrict__ beta, float* __restrict__ sc, int n) {
    int c = threadIdx.x;
    if (c < OUT) {
        float mu = sums[c] / n;
        float var = sums[OUT + c] / n - mu * mu;
        float s = gamma[c] * rsqrtf(var + EPS);
        sc[c] = s;
        sc[OUT + c] = beta[c] - mu * s;
    }
}

// ---------------- Pooling (applies BN3+ReLU inline) + FC ----------------
// Post-ReLU values are >= 0, so int-bit atomicMax with 0-init is exact.

__global__ void k_pool(const float* __restrict__ h, const int* __restrict__ batch,
                       const float* __restrict__ sc, float* __restrict__ pooled, int n) {
    const int K = 128;
    int c = threadIdx.x;            // 0..127
    float scale = sc[c], shift = sc[128 + c];
    int n0 = blockIdx.x * K;
    if (n0 >= n) return;
    int nend = min(n, n0 + K);
    int curg = batch[n0];
    float m = 0.f;
    for (int nn = n0; nn < nend; ++nn) {
        int g = batch[nn];
        if (g != curg) {
            atomicMax((int*)&pooled[curg * 128 + c], __float_as_int(m));
            m = 0.f; curg = g;
        }
        float v = h[(size_t)nn * 128 + c] * scale + shift;
        m = fmaxf(m, v > 0.f ? v : 0.f);
    }
    atomicMax((int*)&pooled[curg * 128 + c], __float_as_int(m));
}

__global__ void k_fc(const float* __restrict__ pooled, const float* __restrict__ fcw,
                     const float* __restrict__ fcb, float* __restrict__ out) {
    int t = threadIdx.x;
    if (t >= NG * 10) return;
    int g = t / 10, j = t % 10;
    float acc = fcb[j];
#pragma unroll
    for (int c = 0; c < 128; ++c) acc += pooled[g * 128 + c] * fcw[c * 10 + j];
    out[g * 10 + j] = acc;
}

// ---------------- Host launch ----------------

extern "C" void kernel_launch(void* const* d_in, const int* in_sizes, int n_in,
                              void* d_out, int out_size, void* d_ws, size_t ws_size,
                              hipStream_t stream) {
    const float* x   = (const float*)d_in[0];
    const int*   ei  = (const int*)d_in[1];
    const int*   bat = (const int*)d_in[2];
    const float* W1  = (const float*)d_in[3];
    const float* as1 = (const float*)d_in[4];
    const float* ad1 = (const float*)d_in[5];
    // d_in[6] = b1 (cancels under BN)
    const float* g1  = (const float*)d_in[7];
    const float* be1 = (const float*)d_in[8];
    const float* W2  = (const float*)d_in[9];
    const float* as2 = (const float*)d_in[10];
    const float* ad2 = (const float*)d_in[11];
    const float* g2  = (const float*)d_in[13];
    const float* be2 = (const float*)d_in[14];
    const float* W3  = (const float*)d_in[15];
    const float* as3 = (const float*)d_in[16];
    const float* ad3 = (const float*)d_in[17];
    const float* g3  = (const float*)d_in[19];
    const float* be3 = (const float*)d_in[20];
    const float* fcw = (const float*)d_in[21];
    const float* fcb = (const float*)d_in[22];
    float* out = (float*)d_out;

    char* w = (char*)d_ws;
    size_t off = 0;
    auto take = [&](size_t bytes) {
        void* p = w + off;
        off += (bytes + 255) & ~(size_t)255;
        return p;
    };
    int*   deg     = (int*)take((size_t)NN * 4);
    int*   cursor  = (int*)take((size_t)NN * 4);
    int*   rowptr  = (int*)take((size_t)(NN + 1) * 4);
    int*   partial = (int*)take(512 * 4);
    int*   colsrc  = (int*)take((size_t)TE * 4);
    float* al_s    = (float*)take((size_t)NN * 2 * 4);
    float* al_d    = (float*)take((size_t)NN * 2 * 4);
    float* bnsums  = (float*)take(256 * 4);
    float* bnsc1   = (float*)take(64 * 4);
    float* bnsc2   = (float*)take(128 * 4);
    float* bnsc3   = (float*)take(256 * 4);
    float* pooled  = (float*)take((size_t)NG * 128 * 4);
    unsigned short* h0 = (unsigned short*)take((size_t)NN * 128 * 2);  // bf16
    float* h1      = (float*)take((size_t)NN * 128 * 4);

    // ---- CSR build ----
    hipMemsetAsync(deg, 0, (size_t)NN * 4, stream);
    k_deg<<<(TE + 255) / 256, 256, 0, stream>>>(ei, deg);
    int nb = (NN + SCAN_B - 1) / SCAN_B;   // 391
    k_scan1<<<nb, SCAN_B, 0, stream>>>(deg, partial, NN);
    k_scan2<<<1, 512, 0, stream>>>(partial, nb, rowptr, NN);
    k_scan3<<<nb, SCAN_B, 0, stream>>>(deg, partial, rowptr, NN);
    hipMemsetAsync(cursor, 0, (size_t)NN * 4, stream);
    k_fill<<<(TE + 255) / 256, 256, 0, stream>>>(ei, rowptr, cursor, colsrc);

    const int AGG_BLOCKS = (NN + 3) / 4;   // 4 waves / block

    // ---- layer 1: 3 -> 32 (H=2, C=16) ----
    k_transform<3, 32, false><<<(NN + 31) / 32, 256, 0, stream>>>(
        x, W1, as1, ad1, nullptr, h0, al_s, al_d, NN);
    k_aggregate<32><<<AGG_BLOCKS, 256, 0, stream>>>(rowptr, colsrc, h0, al_s, al_d, h1);
    hipMemsetAsync(bnsums, 0, 2 * 32 * 4, stream);
    k_bnstats<32><<<512, 256, 0, stream>>>(h1, bnsums, NN);
    k_bnfinal<32><<<1, 32, 0, stream>>>(bnsums, g1, be1, bnsc1, NN);

    // ---- layer 2: 32 -> 64 (H=2, C=32) ----
    k_transform<32, 64, true><<<(NN + 15) / 16, 256, 0, stream>>>(
        h1, W2, as2, ad2, bnsc1, h0, al_s, al_d, NN);
    k_aggregate<64><<<AGG_BLOCKS, 256, 0, stream>>>(rowptr, colsrc, h0, al_s, al_d, h1);
    hipMemsetAsync(bnsums, 0, 2 * 64 * 4, stream);
    k_bnstats<64><<<512, 256, 0, stream>>>(h1, bnsums, NN);
    k_bnfinal<64><<<1, 64, 0, stream>>>(bnsums, g2, be2, bnsc2, NN);

    // ---- layer 3: 64 -> 128 (H=2, C=64) ----
    k_transform<64, 128, true><<<(NN + 7) / 8, 256, 0, stream>>>(
        h1, W3, as3, ad3, bnsc2, h0, al_s, al_d, NN);
    k_aggregate<128><<<AGG_BLOCKS, 256, 0, stream>>>(rowptr, colsrc, h0, al_s, al_d, h1);
    hipMemsetAsync(bnsums, 0, 2 * 128 * 4, stream);
    k_bnstats<128><<<512, 256, 0, stream>>>(h1, bnsums, NN);
    k_bnfinal<128><<<1, 128, 0, stream>>>(bnsums, g3, be3, bnsc3, NN);

    // ---- pool (BN3 fused) + fc ----
    hipMemsetAsync(pooled, 0, (size_t)NG * 128 * 4, stream);
    k_pool<<<(NN + 127) / 128, 128, 0, stream>>>(h1, bat, bnsc3, pooled, NN);
    k_fc<<<1, 640, 0, stream>>>(pooled, fcw, fcb, out);
}

// Round 4
// 562.540 us; speedup vs baseline: 2.3204x; 1.0878x over previous
//
#include <hip/hip_runtime.h>
#include <cstddef>

// Problem constants (fixed by the reference setup)
constexpr int NN = 100000;          // nodes
constexpr int NE = 1600000;         // edges (without self loops)
constexpr int TE = NE + NN;         // edges + self loops = 1,700,000
constexpr int NG = 64;              // graphs
constexpr float EPS = 1e-5f;
constexpr float NEG_SLOPE = 0.2f;
constexpr int NREP = 16;            // BN partial-sum replicas

// bf16 helpers (RNE pack, exact unpack)
__device__ __forceinline__ unsigned short f2bf(float f) {
    unsigned u = __float_as_uint(f);
    u += 0x7fffu + ((u >> 16) & 1u);
    return (unsigned short)(u >> 16);
}
__device__ __forceinline__ float bf2f(unsigned short s) {
    return __uint_as_float((unsigned)s << 16);
}
__device__ __forceinline__ float bflo(unsigned u) { return __uint_as_float(u << 16); }
__device__ __forceinline__ float bfhi(unsigned u) { return __uint_as_float(u & 0xffff0000u); }

// ---------------- CSR build ----------------

__global__ void k_deg(const int* __restrict__ ei, int* __restrict__ deg) {
    int e = blockIdx.x * blockDim.x + threadIdx.x;
    if (e >= TE) return;
    int d = (e < NE) ? ei[NE + e] : (e - NE);
    atomicAdd(&deg[d], 1);
}

#define SCAN_B 256
__global__ void k_scan1(const int* __restrict__ deg, int* __restrict__ partial, int n) {
    __shared__ int ls[SCAN_B];
    int i = blockIdx.x * SCAN_B + threadIdx.x;
    ls[threadIdx.x] = (i < n) ? deg[i] : 0;
    __syncthreads();
    for (int off = SCAN_B / 2; off; off >>= 1) {
        if (threadIdx.x < off) ls[threadIdx.x] += ls[threadIdx.x + off];
        __syncthreads();
    }
    if (threadIdx.x == 0) partial[blockIdx.x] = ls[0];
}

// parallel exclusive scan of the (<=512) per-block partials
__global__ void k_scan2(int* __restrict__ partial, int nb, int* __restrict__ rowptr, int n) {
    __shared__ int ls[512];
    int t = threadIdx.x;
    int v = (t < nb) ? partial[t] : 0;
    ls[t] = v;
    __syncthreads();
    for (int off = 1; off < 512; off <<= 1) {
        int add = (t >= off) ? ls[t - off] : 0;
        __syncthreads();
        ls[t] += add;
        __syncthreads();
    }
    if (t < nb) partial[t] = ls[t] - v;   // exclusive
    if (t == 511) rowptr[n] = ls[511];    // total == TE
}

__global__ void k_scan3(const int* __restrict__ deg, const int* __restrict__ partial,
                        int* __restrict__ rowptr, int n) {
    __shared__ int ls[SCAN_B];
    int i = blockIdx.x * SCAN_B + threadIdx.x;
    int v = (i < n) ? deg[i] : 0;
    ls[threadIdx.x] = v;
    __syncthreads();
    for (int off = 1; off < SCAN_B; off <<= 1) {
        int add = (threadIdx.x >= off) ? ls[threadIdx.x - off] : 0;
        __syncthreads();
        ls[threadIdx.x] += add;
        __syncthreads();
    }
    if (i < n) rowptr[i] = partial[blockIdx.x] + ls[threadIdx.x] - v;  // exclusive
}

// colsrc is written via atomicExch: device-scope atomics execute at the shared
// memory-side cache (not the XCD-private L2), so the 16 scattered 4B writes per
// 64B line coalesce at one coherent point instead of bouncing + RMW-flushing.
__global__ void k_fill(const int* __restrict__ ei, const int* __restrict__ rowptr,
                       int* __restrict__ cursor, int* __restrict__ colsrc) {
    int e = blockIdx.x * blockDim.x + threadIdx.x;
    if (e >= TE) return;
    int s, d;
    if (e < NE) { s = ei[e]; d = ei[NE + e]; } else { s = e - NE; d = e - NE; }
    int pos = atomicAdd(&cursor[d], 1);
    atomicExch(&colsrc[rowptr[d] + pos], s);
}

// ---------------- Node transform: h = bnrelu(x) @ W ; attention dots ----------------
// BN(+ReLU) of the PREVIOUS layer is fused into the LDS load (bias b of the GAT
// layer cancels under BN mean-subtraction, so it is dropped entirely).
// h is written as bf16 (the aggregate gather is its only consumer);
// attention logits als/ald stay fp32 (computed from fp32 accumulators).

template <int IN, int OUT, bool BN>
__global__ void k_transform(const float* __restrict__ x, const float* __restrict__ W,
                            const float* __restrict__ a_src, const float* __restrict__ a_dst,
                            const float* __restrict__ bnsc,   // [IN scale][IN shift]
                            unsigned short* __restrict__ h, float* __restrict__ als,
                            float* __restrict__ ald, int n) {
    constexpr int C = OUT / 2;       // channels per head
    constexpr int TPN = OUT / 4;     // threads per node (float4 per thread)
    constexpr int NB = 256 / TPN;    // nodes per block
    __shared__ float4 Ws4[IN * TPN];
    __shared__ float xs[NB * IN];
    int node0 = blockIdx.x * NB;
    float* Wsf = (float*)Ws4;
    for (int i = threadIdx.x; i < IN * OUT; i += 256) Wsf[i] = W[i];
    for (int i = threadIdx.x; i < NB * IN; i += 256) {
        int nn = node0 + i / IN, ic = i % IN;
        float v = (nn < n) ? x[(size_t)nn * IN + ic] : 0.f;
        if constexpr (BN) {
            v = v * bnsc[ic] + bnsc[IN + ic];
            v = v > 0.f ? v : 0.f;
        }
        xs[i] = v;
    }
    __syncthreads();
    int nl = threadIdx.x / TPN, q = threadIdx.x % TPN;
    int node = node0 + nl;
    float4 acc = {0.f, 0.f, 0.f, 0.f};
#pragma unroll
    for (int i = 0; i < IN; ++i) {
        float xv = xs[nl * IN + i];
        float4 w = Ws4[i * TPN + q];
        acc.x += xv * w.x; acc.y += xv * w.y; acc.z += xv * w.z; acc.w += xv * w.w;
    }
    if (node < n) {
        uint2 pk;
        pk.x = (unsigned)f2bf(acc.x) | ((unsigned)f2bf(acc.y) << 16);
        pk.y = (unsigned)f2bf(acc.z) | ((unsigned)f2bf(acc.w) << 16);
        *(uint2*)&h[(size_t)node * OUT + q * 4] = pk;
    }
    // attention dots: reduce acc . a over the TPN/2 threads of each (node, head)
    int hd = (q >= TPN / 2);
    int cc = (q - hd * (TPN / 2)) * 4;
    float4 as4 = *(const float4*)&a_src[hd * C + cc];
    float4 ad4 = *(const float4*)&a_dst[hd * C + cc];
    float ps = acc.x * as4.x + acc.y * as4.y + acc.z * as4.z + acc.w * as4.w;
    float pd = acc.x * ad4.x + acc.y * ad4.y + acc.z * ad4.z + acc.w * ad4.w;
#pragma unroll
    for (int m = 1; m < TPN / 2; m <<= 1) {
        ps += __shfl_xor(ps, m, 64);
        pd += __shfl_xor(pd, m, 64);
    }
    if ((q & (TPN / 2 - 1)) == 0 && node < n) {
        als[node * 2 + hd] = ps;
        ald[node * 2 + hd] = pd;
    }
}

// ---------------- Aggregation: wave per dst node, bf16 h gather ----------------
// Epilogue accumulates BN statistics (sum, sum-of-squares per channel) via a
// per-block LDS reduce + atomicAdd into NREP-replicated global partials.

__device__ __forceinline__ float lrelu(float v) { return v > 0.f ? v : NEG_SLOPE * v; }

template <int OUT>
__global__ void k_aggregate(const int* __restrict__ rowptr, const int* __restrict__ colsrc,
                            const unsigned short* __restrict__ h, const float* __restrict__ als,
                            const float* __restrict__ ald, float* __restrict__ out,
                            float* __restrict__ bnrep) {
    constexpr int LPE = OUT / 8;   // lanes per edge (8 bf16 = 16B per lane)
    constexpr int EPI = 64 / LPE;  // edges per gather iteration
    __shared__ float rowbuf[4][OUT];
    int wv = threadIdx.x >> 6;
    int wid = (int)(((size_t)blockIdx.x * blockDim.x + threadIdx.x) >> 6);
    int lane = threadIdx.x & 63;
    bool valid = wid < NN;

    if (!valid) {
        for (int c = lane; c < OUT; c += 64) rowbuf[wv][c] = 0.f;
    } else {
        int start = rowptr[wid], end = rowptr[wid + 1];
        int cnt = end - start;
        float2 dv = ((const float2*)ald)[wid];

        if (cnt <= 64) {
            // ---- fast path: whole neighbor list fits one wave ----
            int e = start + lane;
            bool act = e < end;
            int s = act ? colsrc[e] : 0;                 // coalesced
            float2 av = act ? ((const float2*)als)[s] : make_float2(0.f, 0.f);
            float t0 = act ? lrelu(av.x + dv.x) : -1e30f;
            float t1 = act ? lrelu(av.y + dv.y) : -1e30f;
            float m0 = t0, m1 = t1;
#pragma unroll
            for (int off = 32; off; off >>= 1) {
                m0 = fmaxf(m0, __shfl_xor(m0, off, 64));
                m1 = fmaxf(m1, __shfl_xor(m1, off, 64));
            }
            float w0 = act ? __expf(t0 - m0) : 0.f;
            float w1 = act ? __expf(t1 - m1) : 0.f;
            int sub = lane / LPE, cl = lane % LPE;       // cl*8 = first channel
            bool head1 = (cl >= LPE / 2);
            float acc[8];
#pragma unroll
            for (int k = 0; k < 8; ++k) acc[k] = 0.f;
            for (int j0 = 0; j0 < cnt; j0 += EPI) {
                int jj = j0 + sub;                        // < 64 always
                int sj = __shfl(s, jj, 64);
                float w0j = __shfl(w0, jj, 64);
                float w1j = __shfl(w1, jj, 64);
                float wsel = head1 ? w1j : w0j;           // 0 for jj >= cnt
                uint4 hv = *(const uint4*)&h[(size_t)sj * OUT + cl * 8];
                acc[0] += wsel * bflo(hv.x); acc[1] += wsel * bfhi(hv.x);
                acc[2] += wsel * bflo(hv.y); acc[3] += wsel * bfhi(hv.y);
                acc[4] += wsel * bflo(hv.z); acc[5] += wsel * bfhi(hv.z);
                acc[6] += wsel * bflo(hv.w); acc[7] += wsel * bfhi(hv.w);
            }
            // combine edge-slot partials
#pragma unroll
            for (int m = LPE; m < 64; m <<= 1) {
#pragma unroll
                for (int k = 0; k < 8; ++k) acc[k] += __shfl_xor(acc[k], m, 64);
            }
            float den0 = w0, den1 = w1;
#pragma unroll
            for (int off = 32; off; off >>= 1) {
                den0 += __shfl_xor(den0, off, 64);
                den1 += __shfl_xor(den1, off, 64);
            }
            float inv = 1.f / (head1 ? den1 : den0);
            if (sub == 0) {
                float4 o0 = {acc[0] * inv, acc[1] * inv, acc[2] * inv, acc[3] * inv};
                float4 o1 = {acc[4] * inv, acc[5] * inv, acc[6] * inv, acc[7] * inv};
                *(float4*)&out[(size_t)wid * OUT + cl * 8] = o0;
                *(float4*)&out[(size_t)wid * OUT + cl * 8 + 4] = o1;
                *(float4*)&rowbuf[wv][cl * 8] = o0;
                *(float4*)&rowbuf[wv][cl * 8 + 4] = o1;
            }
        } else {
            // ---- slow generic path (deg > 64; essentially never taken) ----
            constexpr int C = OUT / 2;
            float m0 = -1e30f, m1 = -1e30f;
            for (int e = start + lane; e < end; e += 64) {
                int s = colsrc[e];
                float t0 = lrelu(als[s * 2 + 0] + dv.x);
                float t1 = lrelu(als[s * 2 + 1] + dv.y);
                m0 = fmaxf(m0, t0); m1 = fmaxf(m1, t1);
            }
#pragma unroll
            for (int off = 32; off; off >>= 1) {
                m0 = fmaxf(m0, __shfl_xor(m0, off, 64));
                m1 = fmaxf(m1, __shfl_xor(m1, off, 64));
            }
            float den0 = 0.f, den1 = 0.f;
            for (int e = start + lane; e < end; e += 64) {
                int s = colsrc[e];
                float t0 = lrelu(als[s * 2 + 0] + dv.x);
                float t1 = lrelu(als[s * 2 + 1] + dv.y);
                den0 += __expf(t0 - m0); den1 += __expf(t1 - m1);
            }
#pragma unroll
            for (int off = 32; off; off >>= 1) {
                den0 += __shfl_xor(den0, off, 64);
                den1 += __shfl_xor(den1, off, 64);
            }
            float inv0 = 1.f / den0, inv1 = 1.f / den1;
            if constexpr (OUT == 128) {
                float a0 = 0.f, a1 = 0.f;
                for (int e = start; e < end; ++e) {
                    int s = colsrc[e];
                    float t0 = lrelu(als[s * 2 + 0] + dv.x);
                    float t1 = lrelu(als[s * 2 + 1] + dv.y);
                    float w0 = __expf(t0 - m0) * inv0;
                    float w1 = __expf(t1 - m1) * inv1;
                    a0 += w0 * bf2f(h[(size_t)s * OUT + lane]);
                    a1 += w1 * bf2f(h[(size_t)s * OUT + 64 + lane]);
                }
                out[(size_t)wid * OUT + lane] = a0;
                out[(size_t)wid * OUT + 64 + lane] = a1;
                rowbuf[wv][lane] = a0;
                rowbuf[wv][64 + lane] = a1;
            } else {
                int c = lane;
                bool act2 = c < OUT;
                float a0 = 0.f;
                for (int e = start; e < end; ++e) {
                    int s = colsrc[e];
                    float t0 = lrelu(als[s * 2 + 0] + dv.x);
                    float t1 = lrelu(als[s * 2 + 1] + dv.y);
                    float w = (c < C) ? __expf(t0 - m0) * inv0 : __expf(t1 - m1) * inv1;
                    if (act2) a0 += w * bf2f(h[(size_t)s * OUT + c]);
                }
                if (act2) { out[(size_t)wid * OUT + c] = a0; rowbuf[wv][c] = a0; }
            }
        }
    }
    __syncthreads();
    // BN partial sums: reduce 4 rows in LDS, one atomicAdd pair per channel
    float* dst = &bnrep[(blockIdx.x & (NREP - 1)) * 2 * OUT];
    for (int c = threadIdx.x; c < OUT; c += 256) {
        float s = 0.f, ss = 0.f;
#pragma unroll
        for (int wv2 = 0; wv2 < 4; ++wv2) {
            float v = rowbuf[wv2][c];
            s += v; ss += v * v;
        }
        atomicAdd(&dst[c], s);
        atomicAdd(&dst[OUT + c], ss);
    }
}

// ---------------- BN finalize: collapse NREP replicas -> scale/shift ----------------

template <int OUT>
__global__ void k_bnreduce(const float* __restrict__ bnrep, const float* __restrict__ gamma,
                           const float* __restrict__ beta, float* __restrict__ sc, int n) {
    int c = threadIdx.x;
    if (c < OUT) {
        float s = 0.f, ss = 0.f;
        for (int r = 0; r < NREP; ++r) {
            s += bnrep[r * 2 * OUT + c];
            ss += bnrep[r * 2 * OUT + OUT + c];
        }
        float mu = s / n;
        float var = ss / n - mu * mu;
        float sca = gamma[c] * rsqrtf(var + EPS);
        sc[c] = sca;
        sc[OUT + c] = beta[c] - mu * sca;
    }
}

// ---------------- Pooling (applies BN3+ReLU inline) + FC ----------------
// Post-ReLU values are >= 0, so int-bit atomicMax with 0-init is exact.

__global__ void k_pool(const float* __restrict__ h, const int* __restrict__ batch,
                       const float* __restrict__ sc, float* __restrict__ pooled, int n) {
    const int K = 128;
    int c = threadIdx.x;            // 0..127
    float scale = sc[c], shift = sc[128 + c];
    int n0 = blockIdx.x * K;
    if (n0 >= n) return;
    int nend = min(n, n0 + K);
    int curg = batch[n0];
    float m = 0.f;
    for (int nn = n0; nn < nend; ++nn) {
        int g = batch[nn];
        if (g != curg) {
            atomicMax((int*)&pooled[curg * 128 + c], __float_as_int(m));
            m = 0.f; curg = g;
        }
        float v = h[(size_t)nn * 128 + c] * scale + shift;
        m = fmaxf(m, v > 0.f ? v : 0.f);
    }
    atomicMax((int*)&pooled[curg * 128 + c], __float_as_int(m));
}

__global__ void k_fc(const float* __restrict__ pooled, const float* __restrict__ fcw,
                     const float* __restrict__ fcb, float* __restrict__ out) {
    int t = threadIdx.x;
    if (t >= NG * 10) return;
    int g = t / 10, j = t % 10;
    float acc = fcb[j];
#pragma unroll
    for (int c = 0; c < 128; ++c) acc += pooled[g * 128 + c] * fcw[c * 10 + j];
    out[g * 10 + j] = acc;
}

// ---------------- Host launch ----------------

extern "C" void kernel_launch(void* const* d_in, const int* in_sizes, int n_in,
                              void* d_out, int out_size, void* d_ws, size_t ws_size,
                              hipStream_t stream) {
    const float* x   = (const float*)d_in[0];
    const int*   ei  = (const int*)d_in[1];
    const int*   bat = (const int*)d_in[2];
    const float* W1  = (const float*)d_in[3];
    const float* as1 = (const float*)d_in[4];
    const float* ad1 = (const float*)d_in[5];
    // d_in[6] = b1 (cancels under BN)
    const float* g1  = (const float*)d_in[7];
    const float* be1 = (const float*)d_in[8];
    const float* W2  = (const float*)d_in[9];
    const float* as2 = (const float*)d_in[10];
    const float* ad2 = (const float*)d_in[11];
    const float* g2  = (const float*)d_in[13];
    const float* be2 = (const float*)d_in[14];
    const float* W3  = (const float*)d_in[15];
    const float* as3 = (const float*)d_in[16];
    const float* ad3 = (const float*)d_in[17];
    const float* g3  = (const float*)d_in[19];
    const float* be3 = (const float*)d_in[20];
    const float* fcw = (const float*)d_in[21];
    const float* fcb = (const float*)d_in[22];
    float* out = (float*)d_out;

    char* w = (char*)d_ws;
    size_t off = 0;
    auto take = [&](size_t bytes) {
        void* p = w + off;
        off += (bytes + 255) & ~(size_t)255;
        return p;
    };
    // ---- single zero-init region: deg | cursor | bnrep1/2/3 | pooled ----
    constexpr size_t ZN = (size_t)2 * NN + NREP * 2 * (32 + 64 + 128) + NG * 128;
    char* zreg = (char*)take(ZN * 4);
    int*   deg    = (int*)zreg;
    int*   cursor = deg + NN;
    float* bnr1   = (float*)(cursor + NN);           // NREP*64
    float* bnr2   = bnr1 + NREP * 64;                // NREP*128
    float* bnr3   = bnr2 + NREP * 128;               // NREP*256
    float* pooled = bnr3 + NREP * 256;               // NG*128

    int*   rowptr  = (int*)take((size_t)(NN + 1) * 4);
    int*   partial = (int*)take(512 * 4);
    int*   colsrc  = (int*)take((size_t)TE * 4);
    float* al_s    = (float*)take((size_t)NN * 2 * 4);
    float* al_d    = (float*)take((size_t)NN * 2 * 4);
    float* bnsc1   = (float*)take(64 * 4);
    float* bnsc2   = (float*)take(128 * 4);
    float* bnsc3   = (float*)take(256 * 4);
    unsigned short* h0 = (unsigned short*)take((size_t)NN * 128 * 2);  // bf16
    float* h1      = (float*)take((size_t)NN * 128 * 4);

    hipMemsetAsync(zreg, 0, ZN * 4, stream);

    // ---- CSR build ----
    k_deg<<<(TE + 255) / 256, 256, 0, stream>>>(ei, deg);
    int nb = (NN + SCAN_B - 1) / SCAN_B;   // 391
    k_scan1<<<nb, SCAN_B, 0, stream>>>(deg, partial, NN);
    k_scan2<<<1, 512, 0, stream>>>(partial, nb, rowptr, NN);
    k_scan3<<<nb, SCAN_B, 0, stream>>>(deg, partial, rowptr, NN);
    k_fill<<<(TE + 255) / 256, 256, 0, stream>>>(ei, rowptr, cursor, colsrc);

    const int AGG_BLOCKS = (NN + 3) / 4;   // 4 waves / block

    // ---- layer 1: 3 -> 32 (H=2, C=16) ----
    k_transform<3, 32, false><<<(NN + 31) / 32, 256, 0, stream>>>(
        x, W1, as1, ad1, nullptr, h0, al_s, al_d, NN);
    k_aggregate<32><<<AGG_BLOCKS, 256, 0, stream>>>(rowptr, colsrc, h0, al_s, al_d, h1, bnr1);
    k_bnreduce<32><<<1, 64, 0, stream>>>(bnr1, g1, be1, bnsc1, NN);

    // ---- layer 2: 32 -> 64 (H=2, C=32) ----
    k_transform<32, 64, true><<<(NN + 15) / 16, 256, 0, stream>>>(
        h1, W2, as2, ad2, bnsc1, h0, al_s, al_d, NN);
    k_aggregate<64><<<AGG_BLOCKS, 256, 0, stream>>>(rowptr, colsrc, h0, al_s, al_d, h1, bnr2);
    k_bnreduce<64><<<1, 64, 0, stream>>>(bnr2, g2, be2, bnsc2, NN);

    // ---- layer 3: 64 -> 128 (H=2, C=64) ----
    k_transform<64, 128, true><<<(NN + 7) / 8, 256, 0, stream>>>(
        h1, W3, as3, ad3, bnsc2, h0, al_s, al_d, NN);
    k_aggregate<128><<<AGG_BLOCKS, 256, 0, stream>>>(rowptr, colsrc, h0, al_s, al_d, h1, bnr3);
    k_bnreduce<128><<<1, 128, 0, stream>>>(bnr3, g3, be3, bnsc3, NN);

    // ---- pool (BN3 fused) + fc ----
    k_pool<<<(NN + 127) / 128, 128, 0, stream>>>(h1, bat, bnsc3, pooled, NN);
    k_fc<<<1, 640, 0, stream>>>(pooled, fcw, fcb, out);
}

// Round 5
// 410.054 us; speedup vs baseline: 3.1833x; 1.3719x over previous
//
#include <hip/hip_runtime.h>
#include <cstddef>

// Problem constants (fixed by the reference setup)
constexpr int NN = 100000;          // nodes
constexpr int NE = 1600000;         // edges (without self loops)
constexpr int TE = NE + NN;         // edges + self loops = 1,700,000
constexpr int NG = 64;              // graphs
constexpr float EPS = 1e-5f;
constexpr float NEG_SLOPE = 0.2f;
constexpr int NREP = 16;            // BN partial-sum replicas

// CSR bucket sort parameters
constexpr int NBUCK = 256;          // dst buckets
constexpr int DPB = 391;            // dsts per bucket (256*391 >= NN)
constexpr int PHB = 256;            // edge-chunk blocks
constexpr int CH = (TE + PHB - 1) / PHB;   // edges per chunk

// bf16 helpers (RNE pack, exact unpack)
__device__ __forceinline__ unsigned short f2bf(float f) {
    unsigned u = __float_as_uint(f);
    u += 0x7fffu + ((u >> 16) & 1u);
    return (unsigned short)(u >> 16);
}
__device__ __forceinline__ float bf2f(unsigned short s) {
    return __uint_as_float((unsigned)s << 16);
}
__device__ __forceinline__ float bflo(unsigned u) { return __uint_as_float(u << 16); }
__device__ __forceinline__ float bfhi(unsigned u) { return __uint_as_float(u & 0xffff0000u); }

// ---------------- CSR build: bucketed counting sort ----------------
// Goal: every colsrc/pairs cache line is filled by (nearly) one writer in a
// short time window -> no cross-XCD line bouncing, ~1x write traffic.

// phase 1: per-(chunk-block, bucket) histogram
__global__ void k_hist(const int* __restrict__ ei, int* __restrict__ hist) {
    __shared__ int hcnt[NBUCK];
    for (int i = threadIdx.x; i < NBUCK; i += 256) hcnt[i] = 0;
    __syncthreads();
    int k = blockIdx.x;
    int e0 = k * CH, e1 = min(e0 + CH, TE);
    for (int e = e0 + threadIdx.x; e < e1; e += 256) {
        int d = (e < NE) ? ei[NE + e] : (e - NE);
        atomicAdd(&hcnt[d / DPB], 1);
    }
    __syncthreads();
    for (int b = threadIdx.x; b < NBUCK; b += 256) hist[b * PHB + k] = hcnt[b];
}

// phase 2a: exclusive scan within each bucket row (over chunk blocks)
__global__ void k_scanA(int* __restrict__ hist, int* __restrict__ bsum) {
    __shared__ int ls[PHB];
    int b = blockIdx.x, t = threadIdx.x;
    int v = hist[b * PHB + t];
    ls[t] = v;
    __syncthreads();
    for (int off = 1; off < PHB; off <<= 1) {
        int add = (t >= off) ? ls[t - off] : 0;
        __syncthreads();
        ls[t] += add;
        __syncthreads();
    }
    hist[b * PHB + t] = ls[t] - v;      // exclusive
    if (t == PHB - 1) bsum[b] = ls[t];  // bucket total
}

// phase 2b: exclusive scan over bucket totals
__global__ void k_scanB(const int* __restrict__ bsum, int* __restrict__ bbase,
                        int* __restrict__ rowptr) {
    __shared__ int ls[NBUCK];
    int t = threadIdx.x;
    int v = bsum[t];
    ls[t] = v;
    __syncthreads();
    for (int off = 1; off < NBUCK; off <<= 1) {
        int add = (t >= off) ? ls[t - off] : 0;
        __syncthreads();
        ls[t] += add;
        __syncthreads();
    }
    bbase[t] = ls[t] - v;
    if (t == NBUCK - 1) { bbase[NBUCK] = ls[t]; rowptr[NN] = ls[t]; }  // == TE
}

// phase 3: scatter packed (src<<9 | local_dst) into private per-bucket ranges
__global__ void k_scatter(const int* __restrict__ ei, const int* __restrict__ hist,
                          const int* __restrict__ bbase, int* __restrict__ pairs) {
    __shared__ int cur[NBUCK];
    int k = blockIdx.x;
    for (int b = threadIdx.x; b < NBUCK; b += 256) cur[b] = bbase[b] + hist[b * PHB + k];
    __syncthreads();
    int e0 = k * CH, e1 = min(e0 + CH, TE);
    for (int e = e0 + threadIdx.x; e < e1; e += 256) {
        int s, d;
        if (e < NE) { s = ei[e]; d = ei[NE + e]; } else { s = e - NE; d = s; }
        int b = d / DPB, ld = d - b * DPB;
        int pos = atomicAdd(&cur[b], 1);
        pairs[pos] = (s << 9) | ld;
    }
}

// phase 4: one block per bucket -> local deg count, scan, rowptr + colsrc fill.
// colsrc region [base, base+cnt) is contiguous and single-writer.
__global__ void k_csr(const int* __restrict__ pairs, const int* __restrict__ bbase,
                      int* __restrict__ rowptr, int* __restrict__ colsrc) {
    __shared__ int deg[DPB];     // counts, then reused as cursors
    __shared__ int exc[DPB];     // exclusive scan
    __shared__ int sc[512];
    int b = blockIdx.x, t = threadIdx.x;
    int base = bbase[b], cnt = bbase[b + 1] - base;
    int d0 = b * DPB;
    int ndst = min(DPB, NN - d0);
    for (int i = t; i < DPB; i += 256) deg[i] = 0;
    __syncthreads();
    for (int i = t; i < cnt; i += 256) atomicAdd(&deg[pairs[base + i] & 511], 1);
    __syncthreads();
    // inclusive scan of deg (padded to 512), 2 elements per thread
    sc[t] = (t < DPB) ? deg[t] : 0;
    sc[t + 256] = (t + 256 < DPB) ? deg[t + 256] : 0;
    __syncthreads();
    for (int off = 1; off < 512; off <<= 1) {
        int a0 = (t >= off) ? sc[t - off] : 0;
        int a1 = (t + 256 >= off) ? sc[t + 256 - off] : 0;
        __syncthreads();
        sc[t] += a0; sc[t + 256] += a1;
        __syncthreads();
    }
    if (t < DPB) exc[t] = sc[t] - deg[t];
    if (t + 256 < DPB) exc[t + 256] = sc[t + 256] - deg[t + 256];
    __syncthreads();
    for (int i = t; i < ndst; i += 256) rowptr[d0 + i] = base + exc[i];
    for (int i = t; i < DPB; i += 256) deg[i] = 0;   // reuse as cursor
    __syncthreads();
    for (int i = t; i < cnt; i += 256) {
        int p = pairs[base + i];
        int ld = p & 511;
        int s = (unsigned)p >> 9;
        int pos = base + exc[ld] + atomicAdd(&deg[ld], 1);
        colsrc[pos] = s;
    }
}

// ---------------- Node transform: h = bnrelu(x) @ W ; attention dots ----------------
// BN(+ReLU) of the PREVIOUS layer is fused into the LDS load (bias b of the GAT
// layer cancels under BN mean-subtraction, so it is dropped entirely).
// h is written as bf16 (the aggregate gather is its only consumer);
// attention logits als/ald stay fp32 (computed from fp32 accumulators).

template <int IN, int OUT, bool BN>
__global__ void k_transform(const float* __restrict__ x, const float* __restrict__ W,
                            const float* __restrict__ a_src, const float* __restrict__ a_dst,
                            const float* __restrict__ bnsc,   // [IN scale][IN shift]
                            unsigned short* __restrict__ h, float* __restrict__ als,
                            float* __restrict__ ald, int n) {
    constexpr int C = OUT / 2;       // channels per head
    constexpr int TPN = OUT / 4;     // threads per node (float4 per thread)
    constexpr int NB = 256 / TPN;    // nodes per block
    __shared__ float4 Ws4[IN * TPN];
    __shared__ float xs[NB * IN];
    int node0 = blockIdx.x * NB;
    float* Wsf = (float*)Ws4;
    for (int i = threadIdx.x; i < IN * OUT; i += 256) Wsf[i] = W[i];
    for (int i = threadIdx.x; i < NB * IN; i += 256) {
        int nn = node0 + i / IN, ic = i % IN;
        float v = (nn < n) ? x[(size_t)nn * IN + ic] : 0.f;
        if constexpr (BN) {
            v = v * bnsc[ic] + bnsc[IN + ic];
            v = v > 0.f ? v : 0.f;
        }
        xs[i] = v;
    }
    __syncthreads();
    int nl = threadIdx.x / TPN, q = threadIdx.x % TPN;
    int node = node0 + nl;
    float4 acc = {0.f, 0.f, 0.f, 0.f};
#pragma unroll
    for (int i = 0; i < IN; ++i) {
        float xv = xs[nl * IN + i];
        float4 w = Ws4[i * TPN + q];
        acc.x += xv * w.x; acc.y += xv * w.y; acc.z += xv * w.z; acc.w += xv * w.w;
    }
    if (node < n) {
        uint2 pk;
        pk.x = (unsigned)f2bf(acc.x) | ((unsigned)f2bf(acc.y) << 16);
        pk.y = (unsigned)f2bf(acc.z) | ((unsigned)f2bf(acc.w) << 16);
        *(uint2*)&h[(size_t)node * OUT + q * 4] = pk;
    }
    // attention dots: reduce acc . a over the TPN/2 threads of each (node, head)
    int hd = (q >= TPN / 2);
    int cc = (q - hd * (TPN / 2)) * 4;
    float4 as4 = *(const float4*)&a_src[hd * C + cc];
    float4 ad4 = *(const float4*)&a_dst[hd * C + cc];
    float ps = acc.x * as4.x + acc.y * as4.y + acc.z * as4.z + acc.w * as4.w;
    float pd = acc.x * ad4.x + acc.y * ad4.y + acc.z * ad4.z + acc.w * ad4.w;
#pragma unroll
    for (int m = 1; m < TPN / 2; m <<= 1) {
        ps += __shfl_xor(ps, m, 64);
        pd += __shfl_xor(pd, m, 64);
    }
    if ((q & (TPN / 2 - 1)) == 0 && node < n) {
        als[node * 2 + hd] = ps;
        ald[node * 2 + hd] = pd;
    }
}

// ---------------- Aggregation: wave per dst node, bf16 h gather ----------------
// Epilogue accumulates BN statistics (sum, sum-of-squares per channel) via a
// per-block LDS reduce + atomicAdd into NREP-replicated global partials.

__device__ __forceinline__ float lrelu(float v) { return v > 0.f ? v : NEG_SLOPE * v; }

template <int OUT>
__global__ void k_aggregate(const int* __restrict__ rowptr, const int* __restrict__ colsrc,
                            const unsigned short* __restrict__ h, const float* __restrict__ als,
                            const float* __restrict__ ald, float* __restrict__ out,
                            float* __restrict__ bnrep) {
    constexpr int LPE = OUT / 8;   // lanes per edge (8 bf16 = 16B per lane)
    constexpr int EPI = 64 / LPE;  // edges per gather iteration
    __shared__ float rowbuf[4][OUT];
    int wv = threadIdx.x >> 6;
    int wid = (int)(((size_t)blockIdx.x * blockDim.x + threadIdx.x) >> 6);
    int lane = threadIdx.x & 63;
    bool valid = wid < NN;

    if (!valid) {
        for (int c = lane; c < OUT; c += 64) rowbuf[wv][c] = 0.f;
    } else {
        int start = rowptr[wid], end = rowptr[wid + 1];
        int cnt = end - start;
        float2 dv = ((const float2*)ald)[wid];

        if (cnt <= 64) {
            // ---- fast path: whole neighbor list fits one wave ----
            int e = start + lane;
            bool act = e < end;
            int s = act ? colsrc[e] : 0;                 // coalesced
            float2 av = act ? ((const float2*)als)[s] : make_float2(0.f, 0.f);
            float t0 = act ? lrelu(av.x + dv.x) : -1e30f;
            float t1 = act ? lrelu(av.y + dv.y) : -1e30f;
            float m0 = t0, m1 = t1;
#pragma unroll
            for (int off = 32; off; off >>= 1) {
                m0 = fmaxf(m0, __shfl_xor(m0, off, 64));
                m1 = fmaxf(m1, __shfl_xor(m1, off, 64));
            }
            float w0 = act ? __expf(t0 - m0) : 0.f;
            float w1 = act ? __expf(t1 - m1) : 0.f;
            int sub = lane / LPE, cl = lane % LPE;       // cl*8 = first channel
            bool head1 = (cl >= LPE / 2);
            float acc[8];
#pragma unroll
            for (int k = 0; k < 8; ++k) acc[k] = 0.f;
            for (int j0 = 0; j0 < cnt; j0 += EPI) {
                int jj = j0 + sub;                        // < 64 always
                int sj = __shfl(s, jj, 64);
                float w0j = __shfl(w0, jj, 64);
                float w1j = __shfl(w1, jj, 64);
                float wsel = head1 ? w1j : w0j;           // 0 for jj >= cnt
                uint4 hv = *(const uint4*)&h[(size_t)sj * OUT + cl * 8];
                acc[0] += wsel * bflo(hv.x); acc[1] += wsel * bfhi(hv.x);
                acc[2] += wsel * bflo(hv.y); acc[3] += wsel * bfhi(hv.y);
                acc[4] += wsel * bflo(hv.z); acc[5] += wsel * bfhi(hv.z);
                acc[6] += wsel * bflo(hv.w); acc[7] += wsel * bfhi(hv.w);
            }
            // combine edge-slot partials
#pragma unroll
            for (int m = LPE; m < 64; m <<= 1) {
#pragma unroll
                for (int k = 0; k < 8; ++k) acc[k] += __shfl_xor(acc[k], m, 64);
            }
            float den0 = w0, den1 = w1;
#pragma unroll
            for (int off = 32; off; off >>= 1) {
                den0 += __shfl_xor(den0, off, 64);
                den1 += __shfl_xor(den1, off, 64);
            }
            float inv = 1.f / (head1 ? den1 : den0);
            if (sub == 0) {
                float4 o0 = {acc[0] * inv, acc[1] * inv, acc[2] * inv, acc[3] * inv};
                float4 o1 = {acc[4] * inv, acc[5] * inv, acc[6] * inv, acc[7] * inv};
                *(float4*)&out[(size_t)wid * OUT + cl * 8] = o0;
                *(float4*)&out[(size_t)wid * OUT + cl * 8 + 4] = o1;
                *(float4*)&rowbuf[wv][cl * 8] = o0;
                *(float4*)&rowbuf[wv][cl * 8 + 4] = o1;
            }
        } else {
            // ---- slow generic path (deg > 64; essentially never taken) ----
            constexpr int C = OUT / 2;
            float m0 = -1e30f, m1 = -1e30f;
            for (int e = start + lane; e < end; e += 64) {
                int s = colsrc[e];
                float t0 = lrelu(als[s * 2 + 0] + dv.x);
                float t1 = lrelu(als[s * 2 + 1] + dv.y);
                m0 = fmaxf(m0, t0); m1 = fmaxf(m1, t1);
            }
#pragma unroll
            for (int off = 32; off; off >>= 1) {
                m0 = fmaxf(m0, __shfl_xor(m0, off, 64));
                m1 = fmaxf(m1, __shfl_xor(m1, off, 64));
            }
            float den0 = 0.f, den1 = 0.f;
            for (int e = start + lane; e < end; e += 64) {
                int s = colsrc[e];
                float t0 = lrelu(als[s * 2 + 0] + dv.x);
                float t1 = lrelu(als[s * 2 + 1] + dv.y);
                den0 += __expf(t0 - m0); den1 += __expf(t1 - m1);
            }
#pragma unroll
            for (int off = 32; off; off >>= 1) {
                den0 += __shfl_xor(den0, off, 64);
                den1 += __shfl_xor(den1, off, 64);
            }
            float inv0 = 1.f / den0, inv1 = 1.f / den1;
            if constexpr (OUT == 128) {
                float a0 = 0.f, a1 = 0.f;
                for (int e = start; e < end; ++e) {
                    int s = colsrc[e];
                    float t0 = lrelu(als[s * 2 + 0] + dv.x);
                    float t1 = lrelu(als[s * 2 + 1] + dv.y);
                    float w0 = __expf(t0 - m0) * inv0;
                    float w1 = __expf(t1 - m1) * inv1;
                    a0 += w0 * bf2f(h[(size_t)s * OUT + lane]);
                    a1 += w1 * bf2f(h[(size_t)s * OUT + 64 + lane]);
                }
                out[(size_t)wid * OUT + lane] = a0;
                out[(size_t)wid * OUT + 64 + lane] = a1;
                rowbuf[wv][lane] = a0;
                rowbuf[wv][64 + lane] = a1;
            } else {
                int c = lane;
                bool act2 = c < OUT;
                float a0 = 0.f;
                for (int e = start; e < end; ++e) {
                    int s = colsrc[e];
                    float t0 = lrelu(als[s * 2 + 0] + dv.x);
                    float t1 = lrelu(als[s * 2 + 1] + dv.y);
                    float w = (c < C) ? __expf(t0 - m0) * inv0 : __expf(t1 - m1) * inv1;
                    if (act2) a0 += w * bf2f(h[(size_t)s * OUT + c]);
                }
                if (act2) { out[(size_t)wid * OUT + c] = a0; rowbuf[wv][c] = a0; }
            }
        }
    }
    __syncthreads();
    // BN partial sums: reduce 4 rows in LDS, one atomicAdd pair per channel
    float* dst = &bnrep[(blockIdx.x & (NREP - 1)) * 2 * OUT];
    for (int c = threadIdx.x; c < OUT; c += 256) {
        float s = 0.f, ss = 0.f;
#pragma unroll
        for (int wv2 = 0; wv2 < 4; ++wv2) {
            float v = rowbuf[wv2][c];
            s += v; ss += v * v;
        }
        atomicAdd(&dst[c], s);
        atomicAdd(&dst[OUT + c], ss);
    }
}

// ---------------- BN finalize: collapse NREP replicas -> scale/shift ----------------

template <int OUT>
__global__ void k_bnreduce(const float* __restrict__ bnrep, const float* __restrict__ gamma,
                           const float* __restrict__ beta, float* __restrict__ sc, int n) {
    int c = threadIdx.x;
    if (c < OUT) {
        float s = 0.f, ss = 0.f;
        for (int r = 0; r < NREP; ++r) {
            s += bnrep[r * 2 * OUT + c];
            ss += bnrep[r * 2 * OUT + OUT + c];
        }
        float mu = s / n;
        float var = ss / n - mu * mu;
        float sca = gamma[c] * rsqrtf(var + EPS);
        sc[c] = sca;
        sc[OUT + c] = beta[c] - mu * sca;
    }
}

// ---------------- Pooling (applies BN3+ReLU inline) + FC ----------------
// Post-ReLU values are >= 0, so int-bit atomicMax with 0-init is exact.

__global__ void k_pool(const float* __restrict__ h, const int* __restrict__ batch,
                       const float* __restrict__ sc, float* __restrict__ pooled, int n) {
    const int K = 128;
    int c = threadIdx.x;            // 0..127
    float scale = sc[c], shift = sc[128 + c];
    int n0 = blockIdx.x * K;
    if (n0 >= n) return;
    int nend = min(n, n0 + K);
    int curg = batch[n0];
    float m = 0.f;
    for (int nn = n0; nn < nend; ++nn) {
        int g = batch[nn];
        if (g != curg) {
            atomicMax((int*)&pooled[curg * 128 + c], __float_as_int(m));
            m = 0.f; curg = g;
        }
        float v = h[(size_t)nn * 128 + c] * scale + shift;
        m = fmaxf(m, v > 0.f ? v : 0.f);
    }
    atomicMax((int*)&pooled[curg * 128 + c], __float_as_int(m));
}

__global__ void k_fc(const float* __restrict__ pooled, const float* __restrict__ fcw,
                     const float* __restrict__ fcb, float* __restrict__ out) {
    int t = threadIdx.x;
    if (t >= NG * 10) return;
    int g = t / 10, j = t % 10;
    float acc = fcb[j];
#pragma unroll
    for (int c = 0; c < 128; ++c) acc += pooled[g * 128 + c] * fcw[c * 10 + j];
    out[g * 10 + j] = acc;
}

// ---------------- Host launch ----------------

extern "C" void kernel_launch(void* const* d_in, const int* in_sizes, int n_in,
                              void* d_out, int out_size, void* d_ws, size_t ws_size,
                              hipStream_t stream) {
    const float* x   = (const float*)d_in[0];
    const int*   ei  = (const int*)d_in[1];
    const int*   bat = (const int*)d_in[2];
    const float* W1  = (const float*)d_in[3];
    const float* as1 = (const float*)d_in[4];
    const float* ad1 = (const float*)d_in[5];
    // d_in[6] = b1 (cancels under BN)
    const float* g1  = (const float*)d_in[7];
    const float* be1 = (const float*)d_in[8];
    const float* W2  = (const float*)d_in[9];
    const float* as2 = (const float*)d_in[10];
    const float* ad2 = (const float*)d_in[11];
    const float* g2  = (const float*)d_in[13];
    const float* be2 = (const float*)d_in[14];
    const float* W3  = (const float*)d_in[15];
    const float* as3 = (const float*)d_in[16];
    const float* ad3 = (const float*)d_in[17];
    const float* g3  = (const float*)d_in[19];
    const float* be3 = (const float*)d_in[20];
    const float* fcw = (const float*)d_in[21];
    const float* fcb = (const float*)d_in[22];
    float* out = (float*)d_out;

    char* w = (char*)d_ws;
    size_t off = 0;
    auto take = [&](size_t bytes) {
        void* p = w + off;
        off += (bytes + 255) & ~(size_t)255;
        return p;
    };
    // ---- single zero-init region: bnrep1/2/3 | pooled ----
    constexpr size_t ZN = (size_t)NREP * 2 * (32 + 64 + 128) + NG * 128;
    char* zreg = (char*)take(ZN * 4);
    float* bnr1   = (float*)zreg;                    // NREP*64
    float* bnr2   = bnr1 + NREP * 64;                // NREP*128
    float* bnr3   = bnr2 + NREP * 128;               // NREP*256
    float* pooled = bnr3 + NREP * 256;               // NG*128

    int*   hist    = (int*)take((size_t)NBUCK * PHB * 4);
    int*   bsum    = (int*)take(NBUCK * 4);
    int*   bbase   = (int*)take((NBUCK + 1) * 4);
    int*   rowptr  = (int*)take((size_t)(NN + 1) * 4);
    int*   pairs   = (int*)take((size_t)TE * 4);
    int*   colsrc  = (int*)take((size_t)TE * 4);
    float* al_s    = (float*)take((size_t)NN * 2 * 4);
    float* al_d    = (float*)take((size_t)NN * 2 * 4);
    float* bnsc1   = (float*)take(64 * 4);
    float* bnsc2   = (float*)take(128 * 4);
    float* bnsc3   = (float*)take(256 * 4);
    unsigned short* h0 = (unsigned short*)take((size_t)NN * 128 * 2);  // bf16
    float* h1      = (float*)take((size_t)NN * 128 * 4);

    hipMemsetAsync(zreg, 0, ZN * 4, stream);

    // ---- CSR build (bucketed counting sort) ----
    k_hist<<<PHB, 256, 0, stream>>>(ei, hist);
    k_scanA<<<NBUCK, PHB, 0, stream>>>(hist, bsum);
    k_scanB<<<1, NBUCK, 0, stream>>>(bsum, bbase, rowptr);
    k_scatter<<<PHB, 256, 0, stream>>>(ei, hist, bbase, pairs);
    k_csr<<<NBUCK, 256, 0, stream>>>(pairs, bbase, rowptr, colsrc);

    const int AGG_BLOCKS = (NN + 3) / 4;   // 4 waves / block

    // ---- layer 1: 3 -> 32 (H=2, C=16) ----
    k_transform<3, 32, false><<<(NN + 31) / 32, 256, 0, stream>>>(
        x, W1, as1, ad1, nullptr, h0, al_s, al_d, NN);
    k_aggregate<32><<<AGG_BLOCKS, 256, 0, stream>>>(rowptr, colsrc, h0, al_s, al_d, h1, bnr1);
    k_bnreduce<32><<<1, 64, 0, stream>>>(bnr1, g1, be1, bnsc1, NN);

    // ---- layer 2: 32 -> 64 (H=2, C=32) ----
    k_transform<32, 64, true><<<(NN + 15) / 16, 256, 0, stream>>>(
        h1, W2, as2, ad2, bnsc1, h0, al_s, al_d, NN);
    k_aggregate<64><<<AGG_BLOCKS, 256, 0, stream>>>(rowptr, colsrc, h0, al_s, al_d, h1, bnr2);
    k_bnreduce<64><<<1, 64, 0, stream>>>(bnr2, g2, be2, bnsc2, NN);

    // ---- layer 3: 64 -> 128 (H=2, C=64) ----
    k_transform<64, 128, true><<<(NN + 7) / 8, 256, 0, stream>>>(
        h1, W3, as3, ad3, bnsc2, h0, al_s, al_d, NN);
    k_aggregate<128><<<AGG_BLOCKS, 256, 0, stream>>>(rowptr, colsrc, h0, al_s, al_d, h1, bnr3);
    k_bnreduce<128><<<1, 128, 0, stream>>>(bnr3, g3, be3, bnsc3, NN);

    // ---- pool (BN3 fused) + fc ----
    k_pool<<<(NN + 127) / 128, 128, 0, stream>>>(h1, bat, bnsc3, pooled, NN);
    k_fc<<<1, 640, 0, stream>>>(pooled, fcw, fcb, out);
}

// Round 6
// 409.891 us; speedup vs baseline: 3.1846x; 1.0004x over previous
//
#include <hip/hip_runtime.h>
#include <cstddef>

// Problem constants (fixed by the reference setup)
constexpr int NN = 100000;          // nodes
constexpr int NE = 1600000;         // edges (without self loops)
constexpr int TE = NE + NN;         // edges + self loops = 1,700,000
constexpr int NG = 64;              // graphs
constexpr float EPS = 1e-5f;
constexpr float NEG_SLOPE = 0.2f;
constexpr int NREP = 16;            // BN partial-sum replicas

// CSR bucket sort parameters
constexpr int NBUCK = 256;          // dst buckets
constexpr int DPB = 391;            // dsts per bucket (256*391 >= NN)
constexpr int PHB = 256;            // edge-chunk blocks
constexpr int CH = (TE + PHB - 1) / PHB;   // edges per chunk

// bf16 helpers (RNE pack, exact unpack)
__device__ __forceinline__ unsigned short f2bf(float f) {
    unsigned u = __float_as_uint(f);
    u += 0x7fffu + ((u >> 16) & 1u);
    return (unsigned short)(u >> 16);
}
__device__ __forceinline__ float bf2f(unsigned short s) {
    return __uint_as_float((unsigned)s << 16);
}
__device__ __forceinline__ float bflo(unsigned u) { return __uint_as_float(u << 16); }
__device__ __forceinline__ float bfhi(unsigned u) { return __uint_as_float(u & 0xffff0000u); }

// ---------------- CSR build: bucketed counting sort ----------------
// Every colsrc/pairs cache line is filled by (nearly) one writer in a short
// time window -> no cross-XCD line bouncing, ~1x write traffic.

// phase 1: per-(chunk-block, bucket) histogram
__global__ void k_hist(const int* __restrict__ ei, int* __restrict__ hist) {
    __shared__ int hcnt[NBUCK];
    for (int i = threadIdx.x; i < NBUCK; i += 256) hcnt[i] = 0;
    __syncthreads();
    int k = blockIdx.x;
    int e0 = k * CH, e1 = min(e0 + CH, TE);
    for (int e = e0 + threadIdx.x; e < e1; e += 256) {
        int d = (e < NE) ? ei[NE + e] : (e - NE);
        atomicAdd(&hcnt[d / DPB], 1);
    }
    __syncthreads();
    for (int b = threadIdx.x; b < NBUCK; b += 256) hist[b * PHB + k] = hcnt[b];
}

// phase 2a: exclusive scan within each bucket row (over chunk blocks)
__global__ void k_scanA(int* __restrict__ hist, int* __restrict__ bsum) {
    __shared__ int ls[PHB];
    int b = blockIdx.x, t = threadIdx.x;
    int v = hist[b * PHB + t];
    ls[t] = v;
    __syncthreads();
    for (int off = 1; off < PHB; off <<= 1) {
        int add = (t >= off) ? ls[t - off] : 0;
        __syncthreads();
        ls[t] += add;
        __syncthreads();
    }
    hist[b * PHB + t] = ls[t] - v;      // exclusive
    if (t == PHB - 1) bsum[b] = ls[t];  // bucket total
}

// phase 2b: exclusive scan over bucket totals
__global__ void k_scanB(const int* __restrict__ bsum, int* __restrict__ bbase,
                        int* __restrict__ rowptr) {
    __shared__ int ls[NBUCK];
    int t = threadIdx.x;
    int v = bsum[t];
    ls[t] = v;
    __syncthreads();
    for (int off = 1; off < NBUCK; off <<= 1) {
        int add = (t >= off) ? ls[t - off] : 0;
        __syncthreads();
        ls[t] += add;
        __syncthreads();
    }
    bbase[t] = ls[t] - v;
    if (t == NBUCK - 1) { bbase[NBUCK] = ls[t]; rowptr[NN] = ls[t]; }  // == TE
}

// phase 3: scatter packed (src<<9 | local_dst) into private per-bucket ranges
__global__ void k_scatter(const int* __restrict__ ei, const int* __restrict__ hist,
                          const int* __restrict__ bbase, int* __restrict__ pairs) {
    __shared__ int cur[NBUCK];
    int k = blockIdx.x;
    for (int b = threadIdx.x; b < NBUCK; b += 256) cur[b] = bbase[b] + hist[b * PHB + k];
    __syncthreads();
    int e0 = k * CH, e1 = min(e0 + CH, TE);
    for (int e = e0 + threadIdx.x; e < e1; e += 256) {
        int s, d;
        if (e < NE) { s = ei[e]; d = ei[NE + e]; } else { s = e - NE; d = s; }
        int b = d / DPB, ld = d - b * DPB;
        int pos = atomicAdd(&cur[b], 1);
        pairs[pos] = (s << 9) | ld;
    }
}

// phase 4: one block per bucket -> local deg count, scan, rowptr + colsrc fill.
__global__ void k_csr(const int* __restrict__ pairs, const int* __restrict__ bbase,
                      int* __restrict__ rowptr, int* __restrict__ colsrc) {
    __shared__ int deg[DPB];     // counts, then reused as cursors
    __shared__ int exc[DPB];     // exclusive scan
    __shared__ int sc[512];
    int b = blockIdx.x, t = threadIdx.x;
    int base = bbase[b], cnt = bbase[b + 1] - base;
    int d0 = b * DPB;
    int ndst = min(DPB, NN - d0);
    for (int i = t; i < DPB; i += 256) deg[i] = 0;
    __syncthreads();
    for (int i = t; i < cnt; i += 256) atomicAdd(&deg[pairs[base + i] & 511], 1);
    __syncthreads();
    // inclusive scan of deg (padded to 512), 2 elements per thread
    sc[t] = (t < DPB) ? deg[t] : 0;
    sc[t + 256] = (t + 256 < DPB) ? deg[t + 256] : 0;
    __syncthreads();
    for (int off = 1; off < 512; off <<= 1) {
        int a0 = (t >= off) ? sc[t - off] : 0;
        int a1 = (t + 256 >= off) ? sc[t + 256 - off] : 0;
        __syncthreads();
        sc[t] += a0; sc[t + 256] += a1;
        __syncthreads();
    }
    if (t < DPB) exc[t] = sc[t] - deg[t];
    if (t + 256 < DPB) exc[t + 256] = sc[t + 256] - deg[t + 256];
    __syncthreads();
    for (int i = t; i < ndst; i += 256) rowptr[d0 + i] = base + exc[i];
    for (int i = t; i < DPB; i += 256) deg[i] = 0;   // reuse as cursor
    __syncthreads();
    for (int i = t; i < cnt; i += 256) {
        int p = pairs[base + i];
        int ld = p & 511;
        int s = (unsigned)p >> 9;
        int pos = base + exc[ld] + atomicAdd(&deg[ld], 1);
        colsrc[pos] = s;
    }
}

// ---------------- Node transform: h = bnrelu(x) @ W ; attention dots ----------------

template <int IN, int OUT, bool BN>
__global__ void k_transform(const float* __restrict__ x, const float* __restrict__ W,
                            const float* __restrict__ a_src, const float* __restrict__ a_dst,
                            const float* __restrict__ bnsc,   // [IN scale][IN shift]
                            unsigned short* __restrict__ h, float* __restrict__ als,
                            float* __restrict__ ald, int n) {
    constexpr int C = OUT / 2;       // channels per head
    constexpr int TPN = OUT / 4;     // threads per node (float4 per thread)
    constexpr int NB = 256 / TPN;    // nodes per block
    __shared__ float4 Ws4[IN * TPN];
    __shared__ float xs[NB * IN];
    int node0 = blockIdx.x * NB;
    float* Wsf = (float*)Ws4;
    for (int i = threadIdx.x; i < IN * OUT; i += 256) Wsf[i] = W[i];
    for (int i = threadIdx.x; i < NB * IN; i += 256) {
        int nn = node0 + i / IN, ic = i % IN;
        float v = (nn < n) ? x[(size_t)nn * IN + ic] : 0.f;
        if constexpr (BN) {
            v = v * bnsc[ic] + bnsc[IN + ic];
            v = v > 0.f ? v : 0.f;
        }
        xs[i] = v;
    }
    __syncthreads();
    int nl = threadIdx.x / TPN, q = threadIdx.x % TPN;
    int node = node0 + nl;
    float4 acc = {0.f, 0.f, 0.f, 0.f};
#pragma unroll
    for (int i = 0; i < IN; ++i) {
        float xv = xs[nl * IN + i];
        float4 w = Ws4[i * TPN + q];
        acc.x += xv * w.x; acc.y += xv * w.y; acc.z += xv * w.z; acc.w += xv * w.w;
    }
    if (node < n) {
        uint2 pk;
        pk.x = (unsigned)f2bf(acc.x) | ((unsigned)f2bf(acc.y) << 16);
        pk.y = (unsigned)f2bf(acc.z) | ((unsigned)f2bf(acc.w) << 16);
        *(uint2*)&h[(size_t)node * OUT + q * 4] = pk;
    }
    // attention dots: reduce acc . a over the TPN/2 threads of each (node, head)
    int hd = (q >= TPN / 2);
    int cc = (q - hd * (TPN / 2)) * 4;
    float4 as4 = *(const float4*)&a_src[hd * C + cc];
    float4 ad4 = *(const float4*)&a_dst[hd * C + cc];
    float ps = acc.x * as4.x + acc.y * as4.y + acc.z * as4.z + acc.w * as4.w;
    float pd = acc.x * ad4.x + acc.y * ad4.y + acc.z * ad4.z + acc.w * ad4.w;
#pragma unroll
    for (int m = 1; m < TPN / 2; m <<= 1) {
        ps += __shfl_xor(ps, m, 64);
        pd += __shfl_xor(pd, m, 64);
    }
    if ((q & (TPN / 2 - 1)) == 0 && node < n) {
        als[node * 2 + hd] = ps;
        ald[node * 2 + hd] = pd;
    }
}

// ---------------- Aggregation: wave per dst node, bf16 h gather ----------------
// Score phase computes per-edge {src, w0, w1} once and parks it in an LDS edge
// table (one broadcast ds_read_b128 per gather iteration replaces 3 bpermutes).
// Gather tail slots (jj >= cnt) are exec-masked so they issue no VMEM.

__device__ __forceinline__ float lrelu(float v) { return v > 0.f ? v : NEG_SLOPE * v; }

template <int OUT>
__global__ void k_aggregate(const int* __restrict__ rowptr, const int* __restrict__ colsrc,
                            const unsigned short* __restrict__ h, const float* __restrict__ als,
                            const float* __restrict__ ald, float* __restrict__ out,
                            float* __restrict__ bnrep) {
    constexpr int LPE = OUT / 8;   // lanes per edge (8 bf16 = 16B per lane)
    constexpr int EPI = 64 / LPE;  // edges per gather iteration
    __shared__ float rowbuf[4][OUT];
    __shared__ float4 etab[4][64];   // per-wave edge table {s, w0, w1, -}
    int wv = threadIdx.x >> 6;
    int wid = (int)(((size_t)blockIdx.x * blockDim.x + threadIdx.x) >> 6);
    int lane = threadIdx.x & 63;
    bool valid = wid < NN;

    if (!valid) {
        for (int c = lane; c < OUT; c += 64) rowbuf[wv][c] = 0.f;
    } else {
        int start = rowptr[wid], end = rowptr[wid + 1];
        int cnt = end - start;
        float2 dv = ((const float2*)ald)[wid];

        if (cnt <= 64) {
            // ---- fast path: whole neighbor list fits one wave ----
            int e = start + lane;
            bool act = e < end;
            int s = act ? colsrc[e] : 0;                 // coalesced
            float2 av = act ? ((const float2*)als)[s] : make_float2(0.f, 0.f);
            float t0 = act ? lrelu(av.x + dv.x) : -1e30f;
            float t1 = act ? lrelu(av.y + dv.y) : -1e30f;
            float m0 = t0, m1 = t1;
#pragma unroll
            for (int off = 32; off; off >>= 1) {
                m0 = fmaxf(m0, __shfl_xor(m0, off, 64));
                m1 = fmaxf(m1, __shfl_xor(m1, off, 64));
            }
            float w0 = act ? __expf(t0 - m0) : 0.f;
            float w1 = act ? __expf(t1 - m1) : 0.f;
            if (act) etab[wv][lane] = make_float4(__int_as_float(s), w0, w1, 0.f);
            int sub = lane / LPE, cl = lane % LPE;       // cl*8 = first channel
            bool head1 = (cl >= LPE / 2);
            float acc[8];
#pragma unroll
            for (int k = 0; k < 8; ++k) acc[k] = 0.f;
            for (int j0 = 0; j0 < cnt; j0 += EPI) {
                int jj = j0 + sub;
                if (jj < cnt) {                           // exec-masked: no VMEM for tail
                    float4 ed = etab[wv][jj];             // broadcast within sub-group
                    int sj = __float_as_int(ed.x);
                    float wsel = head1 ? ed.z : ed.y;
                    uint4 hv = *(const uint4*)&h[(size_t)sj * OUT + cl * 8];
                    acc[0] += wsel * bflo(hv.x); acc[1] += wsel * bfhi(hv.x);
                    acc[2] += wsel * bflo(hv.y); acc[3] += wsel * bfhi(hv.y);
                    acc[4] += wsel * bflo(hv.z); acc[5] += wsel * bfhi(hv.z);
                    acc[6] += wsel * bflo(hv.w); acc[7] += wsel * bfhi(hv.w);
                }
            }
            // combine edge-slot partials
#pragma unroll
            for (int m = LPE; m < 64; m <<= 1) {
#pragma unroll
                for (int k = 0; k < 8; ++k) acc[k] += __shfl_xor(acc[k], m, 64);
            }
            float den0 = w0, den1 = w1;
#pragma unroll
            for (int off = 32; off; off >>= 1) {
                den0 += __shfl_xor(den0, off, 64);
                den1 += __shfl_xor(den1, off, 64);
            }
            float inv = 1.f / (head1 ? den1 : den0);
            if (sub == 0) {
                float4 o0 = {acc[0] * inv, acc[1] * inv, acc[2] * inv, acc[3] * inv};
                float4 o1 = {acc[4] * inv, acc[5] * inv, acc[6] * inv, acc[7] * inv};
                *(float4*)&out[(size_t)wid * OUT + cl * 8] = o0;
                *(float4*)&out[(size_t)wid * OUT + cl * 8 + 4] = o1;
                *(float4*)&rowbuf[wv][cl * 8] = o0;
                *(float4*)&rowbuf[wv][cl * 8 + 4] = o1;
            }
        } else {
            // ---- slow generic path (deg > 64; essentially never taken) ----
            constexpr int C = OUT / 2;
            float m0 = -1e30f, m1 = -1e30f;
            for (int e = start + lane; e < end; e += 64) {
                int s = colsrc[e];
                float t0 = lrelu(als[s * 2 + 0] + dv.x);
                float t1 = lrelu(als[s * 2 + 1] + dv.y);
                m0 = fmaxf(m0, t0); m1 = fmaxf(m1, t1);
            }
#pragma unroll
            for (int off = 32; off; off >>= 1) {
                m0 = fmaxf(m0, __shfl_xor(m0, off, 64));
                m1 = fmaxf(m1, __shfl_xor(m1, off, 64));
            }
            float den0 = 0.f, den1 = 0.f;
            for (int e = start + lane; e < end; e += 64) {
                int s = colsrc[e];
                float t0 = lrelu(als[s * 2 + 0] + dv.x);
                float t1 = lrelu(als[s * 2 + 1] + dv.y);
                den0 += __expf(t0 - m0); den1 += __expf(t1 - m1);
            }
#pragma unroll
            for (int off = 32; off; off >>= 1) {
                den0 += __shfl_xor(den0, off, 64);
                den1 += __shfl_xor(den1, off, 64);
            }
            float inv0 = 1.f / den0, inv1 = 1.f / den1;
            if constexpr (OUT == 128) {
                float a0 = 0.f, a1 = 0.f;
                for (int e = start; e < end; ++e) {
                    int s = colsrc[e];
                    float t0 = lrelu(als[s * 2 + 0] + dv.x);
                    float t1 = lrelu(als[s * 2 + 1] + dv.y);
                    float w0 = __expf(t0 - m0) * inv0;
                    float w1 = __expf(t1 - m1) * inv1;
                    a0 += w0 * bf2f(h[(size_t)s * OUT + lane]);
                    a1 += w1 * bf2f(h[(size_t)s * OUT + 64 + lane]);
                }
                out[(size_t)wid * OUT + lane] = a0;
                out[(size_t)wid * OUT + 64 + lane] = a1;
                rowbuf[wv][lane] = a0;
                rowbuf[wv][64 + lane] = a1;
            } else {
                int c = lane;
                bool act2 = c < OUT;
                float a0 = 0.f;
                for (int e = start; e < end; ++e) {
                    int s = colsrc[e];
                    float t0 = lrelu(als[s * 2 + 0] + dv.x);
                    float t1 = lrelu(als[s * 2 + 1] + dv.y);
                    float w = (c < C) ? __expf(t0 - m0) * inv0 : __expf(t1 - m1) * inv1;
                    if (act2) a0 += w * bf2f(h[(size_t)s * OUT + c]);
                }
                if (act2) { out[(size_t)wid * OUT + c] = a0; rowbuf[wv][c] = a0; }
            }
        }
    }
    __syncthreads();
    // BN partial sums: reduce 4 rows in LDS, one atomicAdd pair per channel
    float* dst = &bnrep[(blockIdx.x & (NREP - 1)) * 2 * OUT];
    for (int c = threadIdx.x; c < OUT; c += 256) {
        float s = 0.f, ss = 0.f;
#pragma unroll
        for (int wv2 = 0; wv2 < 4; ++wv2) {
            float v = rowbuf[wv2][c];
            s += v; ss += v * v;
        }
        atomicAdd(&dst[c], s);
        atomicAdd(&dst[OUT + c], ss);
    }
}

// ---------------- BN finalize: collapse NREP replicas -> scale/shift ----------------

template <int OUT>
__global__ void k_bnreduce(const float* __restrict__ bnrep, const float* __restrict__ gamma,
                           const float* __restrict__ beta, float* __restrict__ sc, int n) {
    int c = threadIdx.x;
    if (c < OUT) {
        float s = 0.f, ss = 0.f;
        for (int r = 0; r < NREP; ++r) {
            s += bnrep[r * 2 * OUT + c];
            ss += bnrep[r * 2 * OUT + OUT + c];
        }
        float mu = s / n;
        float var = ss / n - mu * mu;
        float sca = gamma[c] * rsqrtf(var + EPS);
        sc[c] = sca;
        sc[OUT + c] = beta[c] - mu * sca;
    }
}

// ---------------- Pooling (applies BN3+ReLU inline) + FC ----------------

__global__ void k_pool(const float* __restrict__ h, const int* __restrict__ batch,
                       const float* __restrict__ sc, float* __restrict__ pooled, int n) {
    const int K = 128;
    int c = threadIdx.x;            // 0..127
    float scale = sc[c], shift = sc[128 + c];
    int n0 = blockIdx.x * K;
    if (n0 >= n) return;
    int nend = min(n, n0 + K);
    int curg = batch[n0];
    float m = 0.f;
    for (int nn = n0; nn < nend; ++nn) {
        int g = batch[nn];
        if (g != curg) {
            atomicMax((int*)&pooled[curg * 128 + c], __float_as_int(m));
            m = 0.f; curg = g;
        }
        float v = h[(size_t)nn * 128 + c] * scale + shift;
        m = fmaxf(m, v > 0.f ? v : 0.f);
    }
    atomicMax((int*)&pooled[curg * 128 + c], __float_as_int(m));
}

__global__ void k_fc(const float* __restrict__ pooled, const float* __restrict__ fcw,
                     const float* __restrict__ fcb, float* __restrict__ out) {
    int t = threadIdx.x;
    if (t >= NG * 10) return;
    int g = t / 10, j = t % 10;
    float acc = fcb[j];
#pragma unroll
    for (int c = 0; c < 128; ++c) acc += pooled[g * 128 + c] * fcw[c * 10 + j];
    out[g * 10 + j] = acc;
}

// ---------------- Host launch ----------------

extern "C" void kernel_launch(void* const* d_in, const int* in_sizes, int n_in,
                              void* d_out, int out_size, void* d_ws, size_t ws_size,
                              hipStream_t stream) {
    const float* x   = (const float*)d_in[0];
    const int*   ei  = (const int*)d_in[1];
    const int*   bat = (const int*)d_in[2];
    const float* W1  = (const float*)d_in[3];
    const float* as1 = (const float*)d_in[4];
    const float* ad1 = (const float*)d_in[5];
    // d_in[6] = b1 (cancels under BN)
    const float* g1  = (const float*)d_in[7];
    const float* be1 = (const float*)d_in[8];
    const float* W2  = (const float*)d_in[9];
    const float* as2 = (const float*)d_in[10];
    const float* ad2 = (const float*)d_in[11];
    const float* g2  = (const float*)d_in[13];
    const float* be2 = (const float*)d_in[14];
    const float* W3  = (const float*)d_in[15];
    const float* as3 = (const float*)d_in[16];
    const float* ad3 = (const float*)d_in[17];
    const float* g3  = (const float*)d_in[19];
    const float* be3 = (const float*)d_in[20];
    const float* fcw = (const float*)d_in[21];
    const float* fcb = (const float*)d_in[22];
    float* out = (float*)d_out;

    char* w = (char*)d_ws;
    size_t off = 0;
    auto take = [&](size_t bytes) {
        void* p = w + off;
        off += (bytes + 255) & ~(size_t)255;
        return p;
    };
    // ---- single zero-init region: bnrep1/2/3 | pooled ----
    constexpr size_t ZN = (size_t)NREP * 2 * (32 + 64 + 128) + NG * 128;
    char* zreg = (char*)take(ZN * 4);
    float* bnr1   = (float*)zreg;                    // NREP*64
    float* bnr2   = bnr1 + NREP * 64;                // NREP*128
    float* bnr3   = bnr2 + NREP * 128;               // NREP*256
    float* pooled = bnr3 + NREP * 256;               // NG*128

    int*   hist    = (int*)take((size_t)NBUCK * PHB * 4);
    int*   bsum    = (int*)take(NBUCK * 4);
    int*   bbase   = (int*)take((NBUCK + 1) * 4);
    int*   rowptr  = (int*)take((size_t)(NN + 1) * 4);
    int*   pairs   = (int*)take((size_t)TE * 4);
    int*   colsrc  = (int*)take((size_t)TE * 4);
    float* al_s    = (float*)take((size_t)NN * 2 * 4);
    float* al_d    = (float*)take((size_t)NN * 2 * 4);
    float* bnsc1   = (float*)take(64 * 4);
    float* bnsc2   = (float*)take(128 * 4);
    float* bnsc3   = (float*)take(256 * 4);
    unsigned short* h0 = (unsigned short*)take((size_t)NN * 128 * 2);  // bf16
    float* h1      = (float*)take((size_t)NN * 128 * 4);

    hipMemsetAsync(zreg, 0, ZN * 4, stream);

    // ---- CSR build (bucketed counting sort) ----
    k_hist<<<PHB, 256, 0, stream>>>(ei, hist);
    k_scanA<<<NBUCK, PHB, 0, stream>>>(hist, bsum);
    k_scanB<<<1, NBUCK, 0, stream>>>(bsum, bbase, rowptr);
    k_scatter<<<PHB, 256, 0, stream>>>(ei, hist, bbase, pairs);
    k_csr<<<NBUCK, 256, 0, stream>>>(pairs, bbase, rowptr, colsrc);

    const int AGG_BLOCKS = (NN + 3) / 4;   // 4 waves / block

    // ---- layer 1: 3 -> 32 (H=2, C=16) ----
    k_transform<3, 32, false><<<(NN + 31) / 32, 256, 0, stream>>>(
        x, W1, as1, ad1, nullptr, h0, al_s, al_d, NN);
    k_aggregate<32><<<AGG_BLOCKS, 256, 0, stream>>>(rowptr, colsrc, h0, al_s, al_d, h1, bnr1);
    k_bnreduce<32><<<1, 64, 0, stream>>>(bnr1, g1, be1, bnsc1, NN);

    // ---- layer 2: 32 -> 64 (H=2, C=32) ----
    k_transform<32, 64, true><<<(NN + 15) / 16, 256, 0, stream>>>(
        h1, W2, as2, ad2, bnsc1, h0, al_s, al_d, NN);
    k_aggregate<64><<<AGG_BLOCKS, 256, 0, stream>>>(rowptr, colsrc, h0, al_s, al_d, h1, bnr2);
    k_bnreduce<64><<<1, 64, 0, stream>>>(bnr2, g2, be2, bnsc2, NN);

    // ---- layer 3: 64 -> 128 (H=2, C=64) ----
    k_transform<64, 128, true><<<(NN + 7) / 8, 256, 0, stream>>>(
        h1, W3, as3, ad3, bnsc2, h0, al_s, al_d, NN);
    k_aggregate<128><<<AGG_BLOCKS, 256, 0, stream>>>(rowptr, colsrc, h0, al_s, al_d, h1, bnr3);
    k_bnreduce<128><<<1, 128, 0, stream>>>(bnr3, g3, be3, bnsc3, NN);

    // ---- pool (BN3 fused) + fc ----
    k_pool<<<(NN + 127) / 128, 128, 0, stream>>>(h1, bat, bnsc3, pooled, NN);
    k_fc<<<1, 640, 0, stream>>>(pooled, fcw, fcb, out);
}

// Round 7
// 409.154 us; speedup vs baseline: 3.1903x; 1.0018x over previous
//
#include <hip/hip_runtime.h>
#include <cstddef>

// Problem constants (fixed by the reference setup)
constexpr int NN = 100000;          // nodes
constexpr int NE = 1600000;         // edges (without self loops)
constexpr int TE = NE + NN;         // edges + self loops = 1,700,000
constexpr int NG = 64;              // graphs
constexpr float EPS = 1e-5f;
constexpr float NEG_SLOPE = 0.2f;
constexpr int NREP = 16;            // BN partial-sum replicas

// CSR bucket sort parameters
constexpr int NBUCK = 256;          // dst buckets
constexpr int DPB = 391;            // dsts per bucket (256*391 >= NN)
constexpr int PHB = 256;            // edge-chunk blocks
constexpr int CH = (TE + PHB - 1) / PHB;   // edges per chunk

// bf16 helpers (RNE pack, exact unpack)
__device__ __forceinline__ unsigned short f2bf(float f) {
    unsigned u = __float_as_uint(f);
    u += 0x7fffu + ((u >> 16) & 1u);
    return (unsigned short)(u >> 16);
}
__device__ __forceinline__ float bf2f(unsigned short s) {
    return __uint_as_float((unsigned)s << 16);
}
__device__ __forceinline__ float bflo(unsigned u) { return __uint_as_float(u << 16); }
__device__ __forceinline__ float bfhi(unsigned u) { return __uint_as_float(u & 0xffff0000u); }

// ---------------- CSR build: bucketed counting sort ----------------

// phase 1: per-(chunk-block, bucket) histogram
__global__ void k_hist(const int* __restrict__ ei, int* __restrict__ hist) {
    __shared__ int hcnt[NBUCK];
    for (int i = threadIdx.x; i < NBUCK; i += 256) hcnt[i] = 0;
    __syncthreads();
    int k = blockIdx.x;
    int e0 = k * CH, e1 = min(e0 + CH, TE);
    for (int e = e0 + threadIdx.x; e < e1; e += 256) {
        int d = (e < NE) ? ei[NE + e] : (e - NE);
        atomicAdd(&hcnt[d / DPB], 1);
    }
    __syncthreads();
    for (int b = threadIdx.x; b < NBUCK; b += 256) hist[b * PHB + k] = hcnt[b];
}

// phase 2a: exclusive scan within each bucket row (over chunk blocks)
__global__ void k_scanA(int* __restrict__ hist, int* __restrict__ bsum) {
    __shared__ int ls[PHB];
    int b = blockIdx.x, t = threadIdx.x;
    int v = hist[b * PHB + t];
    ls[t] = v;
    __syncthreads();
    for (int off = 1; off < PHB; off <<= 1) {
        int add = (t >= off) ? ls[t - off] : 0;
        __syncthreads();
        ls[t] += add;
        __syncthreads();
    }
    hist[b * PHB + t] = ls[t] - v;      // exclusive
    if (t == PHB - 1) bsum[b] = ls[t];  // bucket total
}

// phase 2b: exclusive scan over bucket totals
__global__ void k_scanB(const int* __restrict__ bsum, int* __restrict__ bbase,
                        int* __restrict__ rowptr) {
    __shared__ int ls[NBUCK];
    int t = threadIdx.x;
    int v = bsum[t];
    ls[t] = v;
    __syncthreads();
    for (int off = 1; off < NBUCK; off <<= 1) {
        int add = (t >= off) ? ls[t - off] : 0;
        __syncthreads();
        ls[t] += add;
        __syncthreads();
    }
    bbase[t] = ls[t] - v;
    if (t == NBUCK - 1) { bbase[NBUCK] = ls[t]; rowptr[NN] = ls[t]; }  // == TE
}

// phase 3: scatter packed (src<<9 | local_dst) into private per-bucket ranges
__global__ void k_scatter(const int* __restrict__ ei, const int* __restrict__ hist,
                          const int* __restrict__ bbase, int* __restrict__ pairs) {
    __shared__ int cur[NBUCK];
    int k = blockIdx.x;
    for (int b = threadIdx.x; b < NBUCK; b += 256) cur[b] = bbase[b] + hist[b * PHB + k];
    __syncthreads();
    int e0 = k * CH, e1 = min(e0 + CH, TE);
    for (int e = e0 + threadIdx.x; e < e1; e += 256) {
        int s, d;
        if (e < NE) { s = ei[e]; d = ei[NE + e]; } else { s = e - NE; d = s; }
        int b = d / DPB, ld = d - b * DPB;
        int pos = atomicAdd(&cur[b], 1);
        pairs[pos] = (s << 9) | ld;
    }
}

// phase 4: one block per bucket -> local deg count, scan, rowptr + colsrc fill.
__global__ void k_csr(const int* __restrict__ pairs, const int* __restrict__ bbase,
                      int* __restrict__ rowptr, int* __restrict__ colsrc) {
    __shared__ int deg[DPB];     // counts, then reused as cursors
    __shared__ int exc[DPB];     // exclusive scan
    __shared__ int sc[512];
    int b = blockIdx.x, t = threadIdx.x;
    int base = bbase[b], cnt = bbase[b + 1] - base;
    int d0 = b * DPB;
    int ndst = min(DPB, NN - d0);
    for (int i = t; i < DPB; i += 256) deg[i] = 0;
    __syncthreads();
    for (int i = t; i < cnt; i += 256) atomicAdd(&deg[pairs[base + i] & 511], 1);
    __syncthreads();
    // inclusive scan of deg (padded to 512), 2 elements per thread
    sc[t] = (t < DPB) ? deg[t] : 0;
    sc[t + 256] = (t + 256 < DPB) ? deg[t + 256] : 0;
    __syncthreads();
    for (int off = 1; off < 512; off <<= 1) {
        int a0 = (t >= off) ? sc[t - off] : 0;
        int a1 = (t + 256 >= off) ? sc[t + 256 - off] : 0;
        __syncthreads();
        sc[t] += a0; sc[t + 256] += a1;
        __syncthreads();
    }
    if (t < DPB) exc[t] = sc[t] - deg[t];
    if (t + 256 < DPB) exc[t + 256] = sc[t + 256] - deg[t + 256];
    __syncthreads();
    for (int i = t; i < ndst; i += 256) rowptr[d0 + i] = base + exc[i];
    for (int i = t; i < DPB; i += 256) deg[i] = 0;   // reuse as cursor
    __syncthreads();
    for (int i = t; i < cnt; i += 256) {
        int p = pairs[base + i];
        int ld = p & 511;
        int s = (unsigned)p >> 9;
        int pos = base + exc[ld] + atomicAdd(&deg[ld], 1);
        colsrc[pos] = s;
    }
}

// ---------------- Node transform: h = bnrelu(x) @ W ; attention dots ----------------
// For BN layers the input is bf16 (prev aggregate output) and the BN scale/shift
// is computed inline per block from the NREP-replicated partial sums (L2-hot,
// 4-16 KB) -- no separate bnreduce dispatch. GAT bias b cancels under BN.

template <int IN, int OUT, bool BN>
__global__ void k_transform(const void* __restrict__ xv, const float* __restrict__ W,
                            const float* __restrict__ a_src, const float* __restrict__ a_dst,
                            const float* __restrict__ bnrep,   // [NREP][2*IN] partials
                            const float* __restrict__ gamma, const float* __restrict__ beta,
                            unsigned short* __restrict__ h, float* __restrict__ als,
                            float* __restrict__ ald, int n) {
    constexpr int C = OUT / 2;       // channels per head
    constexpr int TPN = OUT / 4;     // threads per node (float4 per thread)
    constexpr int NB = 256 / TPN;    // nodes per block
    __shared__ float4 Ws4[IN * TPN];
    __shared__ float xs[NB * IN];
    __shared__ float sbn[BN ? 2 * IN : 1];
    int node0 = blockIdx.x * NB;

    if constexpr (BN) {
        if (threadIdx.x < IN) {
            int c = threadIdx.x;
            float s = 0.f, ss = 0.f;
#pragma unroll
            for (int r = 0; r < NREP; ++r) {
                s  += bnrep[r * 2 * IN + c];
                ss += bnrep[r * 2 * IN + IN + c];
            }
            float mu = s / n;
            float var = ss / n - mu * mu;
            float sca = gamma[c] * rsqrtf(var + EPS);
            sbn[c] = sca;
            sbn[IN + c] = beta[c] - mu * sca;
        }
        __syncthreads();
    }

    float* Wsf = (float*)Ws4;
    for (int i = threadIdx.x; i < IN * OUT; i += 256) Wsf[i] = W[i];
    if constexpr (BN) {
        // bf16 input, uint (2 elems) per thread; NB*IN is 512 for both BN layers
        const unsigned* xu = (const unsigned*)xv + (size_t)node0 * IN / 2;
        for (int i = threadIdx.x; i < NB * IN / 2; i += 256) {
            int e0 = 2 * i;
            int nn = node0 + e0 / IN;
            unsigned u = (nn < n) ? xu[i] : 0u;
            int c0 = e0 % IN;
            float v0 = bflo(u) * sbn[c0] + sbn[IN + c0];
            float v1 = bfhi(u) * sbn[c0 + 1] + sbn[IN + c0 + 1];
            xs[e0]     = v0 > 0.f ? v0 : 0.f;
            xs[e0 + 1] = v1 > 0.f ? v1 : 0.f;
        }
    } else {
        const float* x = (const float*)xv;
        for (int i = threadIdx.x; i < NB * IN; i += 256) {
            int nn = node0 + i / IN;
            xs[i] = (nn < n) ? x[(size_t)nn * IN + (i % IN)] : 0.f;
        }
    }
    __syncthreads();
    int nl = threadIdx.x / TPN, q = threadIdx.x % TPN;
    int node = node0 + nl;
    float4 acc = {0.f, 0.f, 0.f, 0.f};
#pragma unroll
    for (int i = 0; i < IN; ++i) {
        float xv2 = xs[nl * IN + i];
        float4 w = Ws4[i * TPN + q];
        acc.x += xv2 * w.x; acc.y += xv2 * w.y; acc.z += xv2 * w.z; acc.w += xv2 * w.w;
    }
    if (node < n) {
        uint2 pk;
        pk.x = (unsigned)f2bf(acc.x) | ((unsigned)f2bf(acc.y) << 16);
        pk.y = (unsigned)f2bf(acc.z) | ((unsigned)f2bf(acc.w) << 16);
        *(uint2*)&h[(size_t)node * OUT + q * 4] = pk;
    }
    // attention dots: reduce acc . a over the TPN/2 threads of each (node, head)
    int hd = (q >= TPN / 2);
    int cc = (q - hd * (TPN / 2)) * 4;
    float4 as4 = *(const float4*)&a_src[hd * C + cc];
    float4 ad4 = *(const float4*)&a_dst[hd * C + cc];
    float ps = acc.x * as4.x + acc.y * as4.y + acc.z * as4.z + acc.w * as4.w;
    float pd = acc.x * ad4.x + acc.y * ad4.y + acc.z * ad4.z + acc.w * ad4.w;
#pragma unroll
    for (int m = 1; m < TPN / 2; m <<= 1) {
        ps += __shfl_xor(ps, m, 64);
        pd += __shfl_xor(pd, m, 64);
    }
    if ((q & (TPN / 2 - 1)) == 0 && node < n) {
        als[node * 2 + hd] = ps;
        ald[node * 2 + hd] = pd;
    }
}

// ---------------- Aggregation: wave per dst node, bf16 h gather, bf16 out ----------------
// BN statistics accumulate from the fp32 accumulators (LDS rowbuf) into
// NREP-replicated global partials; output rows are written as bf16.

__device__ __forceinline__ float lrelu(float v) { return v > 0.f ? v : NEG_SLOPE * v; }

template <int OUT>
__global__ void k_aggregate(const int* __restrict__ rowptr, const int* __restrict__ colsrc,
                            const unsigned short* __restrict__ h, const float* __restrict__ als,
                            const float* __restrict__ ald, unsigned short* __restrict__ out,
                            float* __restrict__ bnrep) {
    constexpr int LPE = OUT / 8;   // lanes per edge (8 bf16 = 16B per lane)
    constexpr int EPI = 64 / LPE;  // edges per gather iteration
    __shared__ float rowbuf[4][OUT];
    __shared__ float4 etab[4][64];   // per-wave edge table {s, w0, w1, -}
    int wv = threadIdx.x >> 6;
    int wid = (int)(((size_t)blockIdx.x * blockDim.x + threadIdx.x) >> 6);
    int lane = threadIdx.x & 63;
    bool valid = wid < NN;

    if (!valid) {
        for (int c = lane; c < OUT; c += 64) rowbuf[wv][c] = 0.f;
    } else {
        int start = rowptr[wid], end = rowptr[wid + 1];
        int cnt = end - start;
        float2 dv = ((const float2*)ald)[wid];

        if (cnt <= 64) {
            // ---- fast path: whole neighbor list fits one wave ----
            int e = start + lane;
            bool act = e < end;
            int s = act ? colsrc[e] : 0;                 // coalesced
            float2 av = act ? ((const float2*)als)[s] : make_float2(0.f, 0.f);
            float t0 = act ? lrelu(av.x + dv.x) : -1e30f;
            float t1 = act ? lrelu(av.y + dv.y) : -1e30f;
            float m0 = t0, m1 = t1;
#pragma unroll
            for (int off = 32; off; off >>= 1) {
                m0 = fmaxf(m0, __shfl_xor(m0, off, 64));
                m1 = fmaxf(m1, __shfl_xor(m1, off, 64));
            }
            float w0 = act ? __expf(t0 - m0) : 0.f;
            float w1 = act ? __expf(t1 - m1) : 0.f;
            if (act) etab[wv][lane] = make_float4(__int_as_float(s), w0, w1, 0.f);
            int sub = lane / LPE, cl = lane % LPE;       // cl*8 = first channel
            bool head1 = (cl >= LPE / 2);
            float acc[8];
#pragma unroll
            for (int k = 0; k < 8; ++k) acc[k] = 0.f;
            for (int j0 = 0; j0 < cnt; j0 += EPI) {
                int jj = j0 + sub;
                if (jj < cnt) {                           // exec-masked tail
                    float4 ed = etab[wv][jj];             // broadcast within sub-group
                    int sj = __float_as_int(ed.x);
                    float wsel = head1 ? ed.z : ed.y;
                    uint4 hv = *(const uint4*)&h[(size_t)sj * OUT + cl * 8];
                    acc[0] += wsel * bflo(hv.x); acc[1] += wsel * bfhi(hv.x);
                    acc[2] += wsel * bflo(hv.y); acc[3] += wsel * bfhi(hv.y);
                    acc[4] += wsel * bflo(hv.z); acc[5] += wsel * bfhi(hv.z);
                    acc[6] += wsel * bflo(hv.w); acc[7] += wsel * bfhi(hv.w);
                }
            }
            // combine edge-slot partials
#pragma unroll
            for (int m = LPE; m < 64; m <<= 1) {
#pragma unroll
                for (int k = 0; k < 8; ++k) acc[k] += __shfl_xor(acc[k], m, 64);
            }
            float den0 = w0, den1 = w1;
#pragma unroll
            for (int off = 32; off; off >>= 1) {
                den0 += __shfl_xor(den0, off, 64);
                den1 += __shfl_xor(den1, off, 64);
            }
            float inv = 1.f / (head1 ? den1 : den0);
            if (sub == 0) {
                float o[8];
#pragma unroll
                for (int k = 0; k < 8; ++k) o[k] = acc[k] * inv;
                uint4 pk;
                pk.x = (unsigned)f2bf(o[0]) | ((unsigned)f2bf(o[1]) << 16);
                pk.y = (unsigned)f2bf(o[2]) | ((unsigned)f2bf(o[3]) << 16);
                pk.z = (unsigned)f2bf(o[4]) | ((unsigned)f2bf(o[5]) << 16);
                pk.w = (unsigned)f2bf(o[6]) | ((unsigned)f2bf(o[7]) << 16);
                *(uint4*)&out[(size_t)wid * OUT + cl * 8] = pk;
                *(float4*)&rowbuf[wv][cl * 8] = make_float4(o[0], o[1], o[2], o[3]);
                *(float4*)&rowbuf[wv][cl * 8 + 4] = make_float4(o[4], o[5], o[6], o[7]);
            }
        } else {
            // ---- slow generic path (deg > 64; essentially never taken) ----
            constexpr int C = OUT / 2;
            float m0 = -1e30f, m1 = -1e30f;
            for (int e = start + lane; e < end; e += 64) {
                int s = colsrc[e];
                float t0 = lrelu(als[s * 2 + 0] + dv.x);
                float t1 = lrelu(als[s * 2 + 1] + dv.y);
                m0 = fmaxf(m0, t0); m1 = fmaxf(m1, t1);
            }
#pragma unroll
            for (int off = 32; off; off >>= 1) {
                m0 = fmaxf(m0, __shfl_xor(m0, off, 64));
                m1 = fmaxf(m1, __shfl_xor(m1, off, 64));
            }
            float den0 = 0.f, den1 = 0.f;
            for (int e = start + lane; e < end; e += 64) {
                int s = colsrc[e];
                float t0 = lrelu(als[s * 2 + 0] + dv.x);
                float t1 = lrelu(als[s * 2 + 1] + dv.y);
                den0 += __expf(t0 - m0); den1 += __expf(t1 - m1);
            }
#pragma unroll
            for (int off = 32; off; off >>= 1) {
                den0 += __shfl_xor(den0, off, 64);
                den1 += __shfl_xor(den1, off, 64);
            }
            float inv0 = 1.f / den0, inv1 = 1.f / den1;
            if constexpr (OUT == 128) {
                float a0 = 0.f, a1 = 0.f;
                for (int e = start; e < end; ++e) {
                    int s = colsrc[e];
                    float t0 = lrelu(als[s * 2 + 0] + dv.x);
                    float t1 = lrelu(als[s * 2 + 1] + dv.y);
                    float w0 = __expf(t0 - m0) * inv0;
                    float w1 = __expf(t1 - m1) * inv1;
                    a0 += w0 * bf2f(h[(size_t)s * OUT + lane]);
                    a1 += w1 * bf2f(h[(size_t)s * OUT + 64 + lane]);
                }
                out[(size_t)wid * OUT + lane] = f2bf(a0);
                out[(size_t)wid * OUT + 64 + lane] = f2bf(a1);
                rowbuf[wv][lane] = a0;
                rowbuf[wv][64 + lane] = a1;
            } else {
                int c = lane;
                bool act2 = c < OUT;
                float a0 = 0.f;
                for (int e = start; e < end; ++e) {
                    int s = colsrc[e];
                    float t0 = lrelu(als[s * 2 + 0] + dv.x);
                    float t1 = lrelu(als[s * 2 + 1] + dv.y);
                    float w = (c < C) ? __expf(t0 - m0) * inv0 : __expf(t1 - m1) * inv1;
                    if (act2) a0 += w * bf2f(h[(size_t)s * OUT + c]);
                }
                if (act2) { out[(size_t)wid * OUT + c] = f2bf(a0); rowbuf[wv][c] = a0; }
            }
        }
    }
    __syncthreads();
    // BN partial sums: reduce 4 rows in LDS, one atomicAdd pair per channel
    float* dst = &bnrep[(blockIdx.x & (NREP - 1)) * 2 * OUT];
    for (int c = threadIdx.x; c < OUT; c += 256) {
        float s = 0.f, ss = 0.f;
#pragma unroll
        for (int wv2 = 0; wv2 < 4; ++wv2) {
            float v = rowbuf[wv2][c];
            s += v; ss += v * v;
        }
        atomicAdd(&dst[c], s);
        atomicAdd(&dst[OUT + c], ss);
    }
}

// ---------------- Pooling (computes BN3 inline, applies +ReLU) + FC ----------------
// Post-ReLU values are >= 0, so int-bit atomicMax with 0-init is exact.

__global__ void k_pool(const unsigned short* __restrict__ h, const int* __restrict__ batch,
                       const float* __restrict__ bnrep, const float* __restrict__ gamma,
                       const float* __restrict__ beta, float* __restrict__ pooled, int n) {
    const int K = 128;
    int c = threadIdx.x;            // 0..127
    float s = 0.f, ss = 0.f;
#pragma unroll
    for (int r = 0; r < NREP; ++r) {
        s  += bnrep[r * 256 + c];
        ss += bnrep[r * 256 + 128 + c];
    }
    float mu = s / n;
    float var = ss / n - mu * mu;
    float scale = gamma[c] * rsqrtf(var + EPS);
    float shift = beta[c] - mu * scale;
    int n0 = blockIdx.x * K;
    if (n0 >= n) return;
    int nend = min(n, n0 + K);
    int curg = batch[n0];
    float m = 0.f;
    for (int nn = n0; nn < nend; ++nn) {
        int g = batch[nn];
        if (g != curg) {
            atomicMax((int*)&pooled[curg * 128 + c], __float_as_int(m));
            m = 0.f; curg = g;
        }
        float v = bf2f(h[(size_t)nn * 128 + c]) * scale + shift;
        m = fmaxf(m, v > 0.f ? v : 0.f);
    }
    atomicMax((int*)&pooled[curg * 128 + c], __float_as_int(m));
}

__global__ void k_fc(const float* __restrict__ pooled, const float* __restrict__ fcw,
                     const float* __restrict__ fcb, float* __restrict__ out) {
    int t = threadIdx.x;
    if (t >= NG * 10) return;
    int g = t / 10, j = t % 10;
    float acc = fcb[j];
#pragma unroll
    for (int c = 0; c < 128; ++c) acc += pooled[g * 128 + c] * fcw[c * 10 + j];
    out[g * 10 + j] = acc;
}

// ---------------- Host launch ----------------

extern "C" void kernel_launch(void* const* d_in, const int* in_sizes, int n_in,
                              void* d_out, int out_size, void* d_ws, size_t ws_size,
                              hipStream_t stream) {
    const float* x   = (const float*)d_in[0];
    const int*   ei  = (const int*)d_in[1];
    const int*   bat = (const int*)d_in[2];
    const float* W1  = (const float*)d_in[3];
    const float* as1 = (const float*)d_in[4];
    const float* ad1 = (const float*)d_in[5];
    // d_in[6] = b1 (cancels under BN)
    const float* g1  = (const float*)d_in[7];
    const float* be1 = (const float*)d_in[8];
    const float* W2  = (const float*)d_in[9];
    const float* as2 = (const float*)d_in[10];
    const float* ad2 = (const float*)d_in[11];
    const float* g2  = (const float*)d_in[13];
    const float* be2 = (const float*)d_in[14];
    const float* W3  = (const float*)d_in[15];
    const float* as3 = (const float*)d_in[16];
    const float* ad3 = (const float*)d_in[17];
    const float* g3  = (const float*)d_in[19];
    const float* be3 = (const float*)d_in[20];
    const float* fcw = (const float*)d_in[21];
    const float* fcb = (const float*)d_in[22];
    float* out = (float*)d_out;

    char* w = (char*)d_ws;
    size_t off = 0;
    auto take = [&](size_t bytes) {
        void* p = w + off;
        off += (bytes + 255) & ~(size_t)255;
        return p;
    };
    // ---- single zero-init region: bnrep1/2/3 | pooled ----
    constexpr size_t ZN = (size_t)NREP * 2 * (32 + 64 + 128) + NG * 128;
    char* zreg = (char*)take(ZN * 4);
    float* bnr1   = (float*)zreg;                    // NREP*64
    float* bnr2   = bnr1 + NREP * 64;                // NREP*128
    float* bnr3   = bnr2 + NREP * 128;               // NREP*256
    float* pooled = bnr3 + NREP * 256;               // NG*128

    int*   hist    = (int*)take((size_t)NBUCK * PHB * 4);
    int*   bsum    = (int*)take(NBUCK * 4);
    int*   bbase   = (int*)take((NBUCK + 1) * 4);
    int*   rowptr  = (int*)take((size_t)(NN + 1) * 4);
    int*   pairs   = (int*)take((size_t)TE * 4);
    int*   colsrc  = (int*)take((size_t)TE * 4);
    float* al_s    = (float*)take((size_t)NN * 2 * 4);
    float* al_d    = (float*)take((size_t)NN * 2 * 4);
    unsigned short* h0 = (unsigned short*)take((size_t)NN * 128 * 2);  // bf16
    unsigned short* h1 = (unsigned short*)take((size_t)NN * 128 * 2);  // bf16

    hipMemsetAsync(zreg, 0, ZN * 4, stream);

    // ---- CSR build (bucketed counting sort) ----
    k_hist<<<PHB, 256, 0, stream>>>(ei, hist);
    k_scanA<<<NBUCK, PHB, 0, stream>>>(hist, bsum);
    k_scanB<<<1, NBUCK, 0, stream>>>(bsum, bbase, rowptr);
    k_scatter<<<PHB, 256, 0, stream>>>(ei, hist, bbase, pairs);
    k_csr<<<NBUCK, 256, 0, stream>>>(pairs, bbase, rowptr, colsrc);

    const int AGG_BLOCKS = (NN + 3) / 4;   // 4 waves / block

    // ---- layer 1: 3 -> 32 (H=2, C=16) ----
    k_transform<3, 32, false><<<(NN + 31) / 32, 256, 0, stream>>>(
        x, W1, as1, ad1, nullptr, nullptr, nullptr, h0, al_s, al_d, NN);
    k_aggregate<32><<<AGG_BLOCKS, 256, 0, stream>>>(rowptr, colsrc, h0, al_s, al_d, h1, bnr1);

    // ---- layer 2: 32 -> 64 (H=2, C=32) ----
    k_transform<32, 64, true><<<(NN + 15) / 16, 256, 0, stream>>>(
        h1, W2, as2, ad2, bnr1, g1, be1, h0, al_s, al_d, NN);
    k_aggregate<64><<<AGG_BLOCKS, 256, 0, stream>>>(rowptr, colsrc, h0, al_s, al_d, h1, bnr2);

    // ---- layer 3: 64 -> 128 (H=2, C=64) ----
    k_transform<64, 128, true><<<(NN + 7) / 8, 256, 0, stream>>>(
        h1, W3, as3, ad3, bnr2, g2, be2, h0, al_s, al_d, NN);
    k_aggregate<128><<<AGG_BLOCKS, 256, 0, stream>>>(rowptr, colsrc, h0, al_s, al_d, h1, bnr3);

    // ---- pool (BN3 inline) + fc ----
    k_pool<<<(NN + 127) / 128, 128, 0, stream>>>(h1, bat, bnr3, g3, be3, pooled, NN);
    k_fc<<<1, 640, 0, stream>>>(pooled, fcw, fcb, out);
}

// Round 8
// 366.328 us; speedup vs baseline: 3.5633x; 1.1169x over previous
//
#include <hip/hip_runtime.h>
#include <cstddef>

// Problem constants (fixed by the reference setup)
constexpr int NN = 100000;          // nodes
constexpr int NE = 1600000;         // edges (without self loops)
constexpr int TE = NE + NN;         // edges + self loops = 1,700,000
constexpr int NG = 64;              // graphs
constexpr float EPS = 1e-5f;
constexpr float NEG_SLOPE = 0.2f;
constexpr int NREP = 16;            // BN partial-sum replicas

// CSR bucket sort parameters
constexpr int NBUCK = 256;          // dst buckets
constexpr int DPB = 391;            // dsts per bucket (256*391 >= NN)
constexpr int PHB = 256;            // edge-chunk blocks
constexpr int CH = (TE + PHB - 1) / PHB;   // edges per chunk

// bf16 helpers (RNE pack, exact unpack)
__device__ __forceinline__ unsigned short f2bf(float f) {
    unsigned u = __float_as_uint(f);
    u += 0x7fffu + ((u >> 16) & 1u);
    return (unsigned short)(u >> 16);
}
__device__ __forceinline__ float bf2f(unsigned short s) {
    return __uint_as_float((unsigned)s << 16);
}
__device__ __forceinline__ float bflo(unsigned u) { return __uint_as_float(u << 16); }
__device__ __forceinline__ float bfhi(unsigned u) { return __uint_as_float(u & 0xffff0000u); }

// ---------------- CSR build: bucketed counting sort ----------------

__global__ void k_hist(const int* __restrict__ ei, int* __restrict__ hist) {
    __shared__ int hcnt[NBUCK];
    for (int i = threadIdx.x; i < NBUCK; i += 256) hcnt[i] = 0;
    __syncthreads();
    int k = blockIdx.x;
    int e0 = k * CH, e1 = min(e0 + CH, TE);
    for (int e = e0 + threadIdx.x; e < e1; e += 256) {
        int d = (e < NE) ? ei[NE + e] : (e - NE);
        atomicAdd(&hcnt[d / DPB], 1);
    }
    __syncthreads();
    for (int b = threadIdx.x; b < NBUCK; b += 256) hist[b * PHB + k] = hcnt[b];
}

__global__ void k_scanA(int* __restrict__ hist, int* __restrict__ bsum) {
    __shared__ int ls[PHB];
    int b = blockIdx.x, t = threadIdx.x;
    int v = hist[b * PHB + t];
    ls[t] = v;
    __syncthreads();
    for (int off = 1; off < PHB; off <<= 1) {
        int add = (t >= off) ? ls[t - off] : 0;
        __syncthreads();
        ls[t] += add;
        __syncthreads();
    }
    hist[b * PHB + t] = ls[t] - v;      // exclusive
    if (t == PHB - 1) bsum[b] = ls[t];  // bucket total
}

__global__ void k_scanB(const int* __restrict__ bsum, int* __restrict__ bbase,
                        int* __restrict__ rowptr) {
    __shared__ int ls[NBUCK];
    int t = threadIdx.x;
    int v = bsum[t];
    ls[t] = v;
    __syncthreads();
    for (int off = 1; off < NBUCK; off <<= 1) {
        int add = (t >= off) ? ls[t - off] : 0;
        __syncthreads();
        ls[t] += add;
        __syncthreads();
    }
    bbase[t] = ls[t] - v;
    if (t == NBUCK - 1) { bbase[NBUCK] = ls[t]; rowptr[NN] = ls[t]; }  // == TE
}

__global__ void k_scatter(const int* __restrict__ ei, const int* __restrict__ hist,
                          const int* __restrict__ bbase, int* __restrict__ pairs) {
    __shared__ int cur[NBUCK];
    int k = blockIdx.x;
    for (int b = threadIdx.x; b < NBUCK; b += 256) cur[b] = bbase[b] + hist[b * PHB + k];
    __syncthreads();
    int e0 = k * CH, e1 = min(e0 + CH, TE);
    for (int e = e0 + threadIdx.x; e < e1; e += 256) {
        int s, d;
        if (e < NE) { s = ei[e]; d = ei[NE + e]; } else { s = e - NE; d = s; }
        int b = d / DPB, ld = d - b * DPB;
        int pos = atomicAdd(&cur[b], 1);
        pairs[pos] = (s << 9) | ld;
    }
}

__global__ void k_csr(const int* __restrict__ pairs, const int* __restrict__ bbase,
                      int* __restrict__ rowptr, int* __restrict__ colsrc) {
    __shared__ int deg[DPB];     // counts, then reused as cursors
    __shared__ int exc[DPB];     // exclusive scan
    __shared__ int sc[512];
    int b = blockIdx.x, t = threadIdx.x;
    int base = bbase[b], cnt = bbase[b + 1] - base;
    int d0 = b * DPB;
    int ndst = min(DPB, NN - d0);
    for (int i = t; i < DPB; i += 256) deg[i] = 0;
    __syncthreads();
    for (int i = t; i < cnt; i += 256) atomicAdd(&deg[pairs[base + i] & 511], 1);
    __syncthreads();
    sc[t] = (t < DPB) ? deg[t] : 0;
    sc[t + 256] = (t + 256 < DPB) ? deg[t + 256] : 0;
    __syncthreads();
    for (int off = 1; off < 512; off <<= 1) {
        int a0 = (t >= off) ? sc[t - off] : 0;
        int a1 = (t + 256 >= off) ? sc[t + 256 - off] : 0;
        __syncthreads();
        sc[t] += a0; sc[t + 256] += a1;
        __syncthreads();
    }
    if (t < DPB) exc[t] = sc[t] - deg[t];
    if (t + 256 < DPB) exc[t + 256] = sc[t + 256] - deg[t + 256];
    __syncthreads();
    for (int i = t; i < ndst; i += 256) rowptr[d0 + i] = base + exc[i];
    for (int i = t; i < DPB; i += 256) deg[i] = 0;   // reuse as cursor
    __syncthreads();
    for (int i = t; i < cnt; i += 256) {
        int p = pairs[base + i];
        int ld = p & 511;
        int s = (unsigned)p >> 9;
        int pos = base + exc[ld] + atomicAdd(&deg[ld], 1);
        colsrc[pos] = s;
    }
}

// ---------------- Node transform: h = bnrelu(x) @ W ; attention dots ----------------
// W is staged once per block and reused across GRP node-groups. BN scale/shift
// computed inline from NREP-replicated partials (L2-hot). GAT bias b cancels.

template <int IN, int OUT, bool BN, int GRP>
__global__ void k_transform(const void* __restrict__ xv, const float* __restrict__ W,
                            const float* __restrict__ a_src, const float* __restrict__ a_dst,
                            const float* __restrict__ bnrep,   // [NREP][2*IN] partials
                            const float* __restrict__ gamma, const float* __restrict__ beta,
                            unsigned short* __restrict__ h, float* __restrict__ als,
                            float* __restrict__ ald, int n) {
    constexpr int C = OUT / 2;       // channels per head
    constexpr int TPN = OUT / 4;     // threads per node (float4 per thread)
    constexpr int NB = 256 / TPN;    // nodes per group
    __shared__ float4 Ws4[IN * TPN];
    __shared__ float xs[NB * IN];
    __shared__ float sbn[BN ? 2 * IN : 1];

    if constexpr (BN) {
        if (threadIdx.x < IN) {
            int c = threadIdx.x;
            float s = 0.f, ss = 0.f;
#pragma unroll
            for (int r = 0; r < NREP; ++r) {
                s  += bnrep[r * 2 * IN + c];
                ss += bnrep[r * 2 * IN + IN + c];
            }
            float mu = s / n;
            float var = ss / n - mu * mu;
            float sca = gamma[c] * rsqrtf(var + EPS);
            sbn[c] = sca;
            sbn[IN + c] = beta[c] - mu * sca;
        }
    }
    float* Wsf = (float*)Ws4;
    for (int i = threadIdx.x; i < IN * OUT; i += 256) Wsf[i] = W[i];
    __syncthreads();

    int nl = threadIdx.x / TPN, q = threadIdx.x % TPN;
    int hd = (q >= TPN / 2);
    int cc = (q - hd * (TPN / 2)) * 4;
    float4 as4 = *(const float4*)&a_src[hd * C + cc];
    float4 ad4 = *(const float4*)&a_dst[hd * C + cc];

    for (int g = 0; g < GRP; ++g) {
        int node0 = (blockIdx.x * GRP + g) * NB;
        if (node0 >= n) break;
        if constexpr (BN) {
            const unsigned* xu = (const unsigned*)xv + (size_t)node0 * IN / 2;
            for (int i = threadIdx.x; i < NB * IN / 2; i += 256) {
                int e0 = 2 * i;
                int nn = node0 + e0 / IN;
                unsigned u = (nn < n) ? xu[i] : 0u;
                int c0 = e0 % IN;
                float v0 = bflo(u) * sbn[c0] + sbn[IN + c0];
                float v1 = bfhi(u) * sbn[c0 + 1] + sbn[IN + c0 + 1];
                xs[e0]     = v0 > 0.f ? v0 : 0.f;
                xs[e0 + 1] = v1 > 0.f ? v1 : 0.f;
            }
        } else {
            const float* x = (const float*)xv;
            for (int i = threadIdx.x; i < NB * IN; i += 256) {
                int nn = node0 + i / IN;
                xs[i] = (nn < n) ? x[(size_t)nn * IN + (i % IN)] : 0.f;
            }
        }
        __syncthreads();
        int node = node0 + nl;
        float4 acc = {0.f, 0.f, 0.f, 0.f};
#pragma unroll
        for (int i = 0; i < IN; ++i) {
            float xv2 = xs[nl * IN + i];
            float4 w = Ws4[i * TPN + q];
            acc.x += xv2 * w.x; acc.y += xv2 * w.y; acc.z += xv2 * w.z; acc.w += xv2 * w.w;
        }
        if (node < n) {
            uint2 pk;
            pk.x = (unsigned)f2bf(acc.x) | ((unsigned)f2bf(acc.y) << 16);
            pk.y = (unsigned)f2bf(acc.z) | ((unsigned)f2bf(acc.w) << 16);
            *(uint2*)&h[(size_t)node * OUT + q * 4] = pk;
        }
        float ps = acc.x * as4.x + acc.y * as4.y + acc.z * as4.z + acc.w * as4.w;
        float pd = acc.x * ad4.x + acc.y * ad4.y + acc.z * ad4.z + acc.w * ad4.w;
#pragma unroll
        for (int m = 1; m < TPN / 2; m <<= 1) {
            ps += __shfl_xor(ps, m, 64);
            pd += __shfl_xor(pd, m, 64);
        }
        if ((q & (TPN / 2 - 1)) == 0 && node < n) {
            als[node * 2 + hd] = ps;
            ald[node * 2 + hd] = pd;
        }
        __syncthreads();   // xs reused next group
    }
}

// ---------------- Aggregation: TWO dst nodes per wave (half-wave each) ----------------
// Fast path handles cnt<=32 per node (covers ~99.99% at mean deg 17); the rare
// deg>32 wave falls back to a 64-lane generic path per node.

__device__ __forceinline__ float lrelu(float v) { return v > 0.f ? v : NEG_SLOPE * v; }

template <int OUT>
__global__ void k_aggregate(const int* __restrict__ rowptr, const int* __restrict__ colsrc,
                            const unsigned short* __restrict__ h, const float* __restrict__ als,
                            const float* __restrict__ ald, unsigned short* __restrict__ out,
                            float* __restrict__ bnrep) {
    constexpr int LPE = OUT / 8;    // lanes per edge (8 bf16 = 16B per lane)
    constexpr int EPI2 = 32 / LPE;  // edges per iteration per half-wave
    __shared__ float rowbuf[8][OUT];
    __shared__ float4 etab[4][64];   // per-wave edge table {s, w0, w1, -}
    int wv = threadIdx.x >> 6;
    int lane = threadIdx.x & 63;
    int hw = lane >> 5, hl = lane & 31;
    int base = ((int)blockIdx.x * 4 + wv) * 2;   // first node of this wave
    int wid = base + hw;                          // node handled by this half
    bool valid = wid < NN;

    int start = 0, cnt = 0;
    float2 dv = make_float2(0.f, 0.f);
    if (valid) {
        start = rowptr[wid];
        cnt = rowptr[wid + 1] - start;
        dv = ((const float2*)ald)[wid];
    }
    int mc = max(cnt, __shfl_xor(cnt, 32, 64));   // wave-uniform max cnt

    if (mc <= 32) {
        // ---- fast path: each half-wave owns one node ----
        int e = start + hl;
        bool act = valid && (hl < cnt);
        int s = act ? colsrc[e] : 0;
        float2 av = act ? ((const float2*)als)[s] : make_float2(0.f, 0.f);
        float t0 = act ? lrelu(av.x + dv.x) : -1e30f;
        float t1 = act ? lrelu(av.y + dv.y) : -1e30f;
        float m0 = t0, m1 = t1;
#pragma unroll
        for (int off = 16; off; off >>= 1) {
            m0 = fmaxf(m0, __shfl_xor(m0, off, 32));
            m1 = fmaxf(m1, __shfl_xor(m1, off, 32));
        }
        float w0 = act ? __expf(t0 - m0) : 0.f;
        float w1 = act ? __expf(t1 - m1) : 0.f;
        float den0 = w0, den1 = w1;
#pragma unroll
        for (int off = 16; off; off >>= 1) {
            den0 += __shfl_xor(den0, off, 32);
            den1 += __shfl_xor(den1, off, 32);
        }
        etab[wv][lane] = make_float4(__int_as_float(s), w0, w1, 0.f);
        int sub = hl / LPE, cl = hl % LPE;
        bool head1 = (cl >= LPE / 2);
        float acc[8];
#pragma unroll
        for (int k = 0; k < 8; ++k) acc[k] = 0.f;
        for (int j0 = 0; j0 < cnt; j0 += EPI2) {
            int jj = j0 + sub;
            if (jj < cnt) {
                float4 ed = etab[wv][hw * 32 + jj];
                int sj = __float_as_int(ed.x);
                float wsel = head1 ? ed.z : ed.y;
                uint4 hv = *(const uint4*)&h[(size_t)sj * OUT + cl * 8];
                acc[0] += wsel * bflo(hv.x); acc[1] += wsel * bfhi(hv.x);
                acc[2] += wsel * bflo(hv.y); acc[3] += wsel * bfhi(hv.y);
                acc[4] += wsel * bflo(hv.z); acc[5] += wsel * bfhi(hv.z);
                acc[6] += wsel * bflo(hv.w); acc[7] += wsel * bfhi(hv.w);
            }
        }
#pragma unroll
        for (int m = LPE; m < 32; m <<= 1) {
#pragma unroll
            for (int k = 0; k < 8; ++k) acc[k] += __shfl_xor(acc[k], m, 32);
        }
        float inv = 1.f / (head1 ? den1 : den0);
        if (valid && sub == 0) {
            float o[8];
#pragma unroll
            for (int k = 0; k < 8; ++k) o[k] = acc[k] * inv;
            uint4 pk;
            pk.x = (unsigned)f2bf(o[0]) | ((unsigned)f2bf(o[1]) << 16);
            pk.y = (unsigned)f2bf(o[2]) | ((unsigned)f2bf(o[3]) << 16);
            pk.z = (unsigned)f2bf(o[4]) | ((unsigned)f2bf(o[5]) << 16);
            pk.w = (unsigned)f2bf(o[6]) | ((unsigned)f2bf(o[7]) << 16);
            *(uint4*)&out[(size_t)wid * OUT + cl * 8] = pk;
            *(float4*)&rowbuf[wv * 2 + hw][cl * 8] = make_float4(o[0], o[1], o[2], o[3]);
            *(float4*)&rowbuf[wv * 2 + hw][cl * 8 + 4] = make_float4(o[4], o[5], o[6], o[7]);
        } else if (!valid) {
            for (int c = hl; c < OUT; c += 32) rowbuf[wv * 2 + hw][c] = 0.f;
        }
    } else {
        // ---- rare fallback: whole wave processes each node generically ----
        for (int i = 0; i < 2; ++i) {
            int w2 = base + i;
            int rb = wv * 2 + i;
            if (w2 >= NN) {
                for (int c = lane; c < OUT; c += 64) rowbuf[rb][c] = 0.f;
                continue;
            }
            int st = rowptr[w2], en = rowptr[w2 + 1];
            float2 dv2 = ((const float2*)ald)[w2];
            constexpr int C = OUT / 2;
            float m0 = -1e30f, m1 = -1e30f;
            for (int e = st + lane; e < en; e += 64) {
                int s = colsrc[e];
                float t0 = lrelu(als[s * 2 + 0] + dv2.x);
                float t1 = lrelu(als[s * 2 + 1] + dv2.y);
                m0 = fmaxf(m0, t0); m1 = fmaxf(m1, t1);
            }
#pragma unroll
            for (int off = 32; off; off >>= 1) {
                m0 = fmaxf(m0, __shfl_xor(m0, off, 64));
                m1 = fmaxf(m1, __shfl_xor(m1, off, 64));
            }
            float den0 = 0.f, den1 = 0.f;
            for (int e = st + lane; e < en; e += 64) {
                int s = colsrc[e];
                float t0 = lrelu(als[s * 2 + 0] + dv2.x);
                float t1 = lrelu(als[s * 2 + 1] + dv2.y);
                den0 += __expf(t0 - m0); den1 += __expf(t1 - m1);
            }
#pragma unroll
            for (int off = 32; off; off >>= 1) {
                den0 += __shfl_xor(den0, off, 64);
                den1 += __shfl_xor(den1, off, 64);
            }
            float inv0 = 1.f / den0, inv1 = 1.f / den1;
            if constexpr (OUT == 128) {
                float a0 = 0.f, a1 = 0.f;
                for (int e = st; e < en; ++e) {
                    int s = colsrc[e];
                    float t0 = lrelu(als[s * 2 + 0] + dv2.x);
                    float t1 = lrelu(als[s * 2 + 1] + dv2.y);
                    float w0 = __expf(t0 - m0) * inv0;
                    float w1 = __expf(t1 - m1) * inv1;
                    a0 += w0 * bf2f(h[(size_t)s * OUT + lane]);
                    a1 += w1 * bf2f(h[(size_t)s * OUT + 64 + lane]);
                }
                out[(size_t)w2 * OUT + lane] = f2bf(a0);
                out[(size_t)w2 * OUT + 64 + lane] = f2bf(a1);
                rowbuf[rb][lane] = a0;
                rowbuf[rb][64 + lane] = a1;
            } else {
                int c = lane;
                bool act2 = c < OUT;
                float a0 = 0.f;
                for (int e = st; e < en; ++e) {
                    int s = colsrc[e];
                    float t0 = lrelu(als[s * 2 + 0] + dv2.x);
                    float t1 = lrelu(als[s * 2 + 1] + dv2.y);
                    float w = (c < C) ? __expf(t0 - m0) * inv0 : __expf(t1 - m1) * inv1;
                    if (act2) a0 += w * bf2f(h[(size_t)s * OUT + c]);
                }
                if (act2) { out[(size_t)w2 * OUT + c] = f2bf(a0); rowbuf[rb][c] = a0; }
            }
        }
    }
    __syncthreads();
    // BN partial sums: reduce 8 rows in LDS, one atomicAdd pair per channel
    float* dst = &bnrep[(blockIdx.x & (NREP - 1)) * 2 * OUT];
    for (int c = threadIdx.x; c < OUT; c += 256) {
        float s = 0.f, ss = 0.f;
#pragma unroll
        for (int r = 0; r < 8; ++r) {
            float v = rowbuf[r][c];
            s += v; ss += v * v;
        }
        atomicAdd(&dst[c], s);
        atomicAdd(&dst[OUT + c], ss);
    }
}

// ---------------- Pooling (computes BN3 inline, applies +ReLU) + FC ----------------

__global__ void k_pool(const unsigned short* __restrict__ h, const int* __restrict__ batch,
                       const float* __restrict__ bnrep, const float* __restrict__ gamma,
                       const float* __restrict__ beta, float* __restrict__ pooled, int n) {
    const int K = 32;               // nodes per block
    int c = threadIdx.x;            // 0..127
    float s = 0.f, ss = 0.f;
#pragma unroll
    for (int r = 0; r < NREP; ++r) {
        s  += bnrep[r * 256 + c];
        ss += bnrep[r * 256 + 128 + c];
    }
    float mu = s / n;
    float var = ss / n - mu * mu;
    float scale = gamma[c] * rsqrtf(var + EPS);
    float shift = beta[c] - mu * scale;
    int n0 = blockIdx.x * K;
    if (n0 >= n) return;
    int nend = min(n, n0 + K);
    int curg = batch[n0];
    float m = 0.f;
    for (int nn = n0; nn < nend; ++nn) {
        int g = batch[nn];
        if (g != curg) {
            atomicMax((int*)&pooled[curg * 128 + c], __float_as_int(m));
            m = 0.f; curg = g;
        }
        float v = bf2f(h[(size_t)nn * 128 + c]) * scale + shift;
        m = fmaxf(m, v > 0.f ? v : 0.f);
    }
    atomicMax((int*)&pooled[curg * 128 + c], __float_as_int(m));
}

__global__ void k_fc(const float* __restrict__ pooled, const float* __restrict__ fcw,
                     const float* __restrict__ fcb, float* __restrict__ out) {
    int t = threadIdx.x;
    if (t >= NG * 10) return;
    int g = t / 10, j = t % 10;
    float acc = fcb[j];
#pragma unroll
    for (int c = 0; c < 128; ++c) acc += pooled[g * 128 + c] * fcw[c * 10 + j];
    out[g * 10 + j] = acc;
}

// ---------------- Host launch ----------------

extern "C" void kernel_launch(void* const* d_in, const int* in_sizes, int n_in,
                              void* d_out, int out_size, void* d_ws, size_t ws_size,
                              hipStream_t stream) {
    const float* x   = (const float*)d_in[0];
    const int*   ei  = (const int*)d_in[1];
    const int*   bat = (const int*)d_in[2];
    const float* W1  = (const float*)d_in[3];
    const float* as1 = (const float*)d_in[4];
    const float* ad1 = (const float*)d_in[5];
    // d_in[6] = b1 (cancels under BN)
    const float* g1  = (const float*)d_in[7];
    const float* be1 = (const float*)d_in[8];
    const float* W2  = (const float*)d_in[9];
    const float* as2 = (const float*)d_in[10];
    const float* ad2 = (const float*)d_in[11];
    const float* g2  = (const float*)d_in[13];
    const float* be2 = (const float*)d_in[14];
    const float* W3  = (const float*)d_in[15];
    const float* as3 = (const float*)d_in[16];
    const float* ad3 = (const float*)d_in[17];
    const float* g3  = (const float*)d_in[19];
    const float* be3 = (const float*)d_in[20];
    const float* fcw = (const float*)d_in[21];
    const float* fcb = (const float*)d_in[22];
    float* out = (float*)d_out;

    char* w = (char*)d_ws;
    size_t off = 0;
    auto take = [&](size_t bytes) {
        void* p = w + off;
        off += (bytes + 255) & ~(size_t)255;
        return p;
    };
    // ---- single zero-init region: bnrep1/2/3 | pooled ----
    constexpr size_t ZN = (size_t)NREP * 2 * (32 + 64 + 128) + NG * 128;
    char* zreg = (char*)take(ZN * 4);
    float* bnr1   = (float*)zreg;                    // NREP*64
    float* bnr2   = bnr1 + NREP * 64;                // NREP*128
    float* bnr3   = bnr2 + NREP * 128;               // NREP*256
    float* pooled = bnr3 + NREP * 256;               // NG*128

    int*   hist    = (int*)take((size_t)NBUCK * PHB * 4);
    int*   bsum    = (int*)take(NBUCK * 4);
    int*   bbase   = (int*)take((NBUCK + 1) * 4);
    int*   rowptr  = (int*)take((size_t)(NN + 1) * 4);
    int*   pairs   = (int*)take((size_t)TE * 4);
    int*   colsrc  = (int*)take((size_t)TE * 4);
    float* al_s    = (float*)take((size_t)NN * 2 * 4);
    float* al_d    = (float*)take((size_t)NN * 2 * 4);
    unsigned short* h0 = (unsigned short*)take((size_t)NN * 128 * 2);  // bf16
    unsigned short* h1 = (unsigned short*)take((size_t)NN * 128 * 2);  // bf16

    hipMemsetAsync(zreg, 0, ZN * 4, stream);

    // ---- CSR build (bucketed counting sort) ----
    k_hist<<<PHB, 256, 0, stream>>>(ei, hist);
    k_scanA<<<NBUCK, PHB, 0, stream>>>(hist, bsum);
    k_scanB<<<1, NBUCK, 0, stream>>>(bsum, bbase, rowptr);
    k_scatter<<<PHB, 256, 0, stream>>>(ei, hist, bbase, pairs);
    k_csr<<<NBUCK, 256, 0, stream>>>(pairs, bbase, rowptr, colsrc);

    const int AGG_BLOCKS = (NN + 7) / 8;   // 4 waves/block, 2 nodes/wave

    // ---- layer 1: 3 -> 32 (H=2, C=16) ----
    k_transform<3, 32, false, 1><<<(NN + 31) / 32, 256, 0, stream>>>(
        x, W1, as1, ad1, nullptr, nullptr, nullptr, h0, al_s, al_d, NN);
    k_aggregate<32><<<AGG_BLOCKS, 256, 0, stream>>>(rowptr, colsrc, h0, al_s, al_d, h1, bnr1);

    // ---- layer 2: 32 -> 64 (H=2, C=32) ----
    k_transform<32, 64, true, 4><<<(NN + 63) / 64, 256, 0, stream>>>(
        h1, W2, as2, ad2, bnr1, g1, be1, h0, al_s, al_d, NN);
    k_aggregate<64><<<AGG_BLOCKS, 256, 0, stream>>>(rowptr, colsrc, h0, al_s, al_d, h1, bnr2);

    // ---- layer 3: 64 -> 128 (H=2, C=64) ----
    k_transform<64, 128, true, 4><<<(NN + 31) / 32, 256, 0, stream>>>(
        h1, W3, as3, ad3, bnr2, g2, be2, h0, al_s, al_d, NN);
    k_aggregate<128><<<AGG_BLOCKS, 256, 0, stream>>>(rowptr, colsrc, h0, al_s, al_d, h1, bnr3);

    // ---- pool (BN3 inline) + fc ----
    k_pool<<<(NN + 31) / 32, 128, 0, stream>>>(h1, bat, bnr3, g3, be3, pooled, NN);
    k_fc<<<1, 640, 0, stream>>>(pooled, fcw, fcb, out);
}